// Round 4
// baseline (505.419 us; speedup 1.0000x reference)
//
#include <hip/hip_runtime.h>
#include <hip/hip_bf16.h>
#include <stdint.h>

// MLA forward: B=2,S=2048,H=2048,NH=16,D=128,LAT=512. Inputs fp32 (R3-proven).
// R13: flash = BN=64 keys/iter (32 iters, was 64). R12 falsified occupancy as
// the lever (43% occ, same speed): the cost is per-iteration overhead + phase
// lockstep from the 1 barrier/iter. Doubling the K-tile halves barrier/stage/
// mask/loop overhead per key and doubles phase lengths (32 QK MFMA, 16 PV MFMA
// back-to-back -> issue-limited, 4 interleaved acc chains). LDS 96KB -> 1 blk/
// CU (2 waves/SIMD, proven-equal R11 vs R12). launch_bounds(512,2): VGPR<=256,
// no spill for ~150 live regs. m214 ladder's KVBLK=64 step was +27% there.
typedef __hip_bfloat16 bf16;
typedef __attribute__((ext_vector_type(8))) short s8v;   // 8 x bf16 (4 VGPRs)
typedef __attribute__((ext_vector_type(4))) float f4v;   // MFMA 16x16 accum

__device__ __forceinline__ void gld16(const bf16* g, bf16* l) {
  __builtin_amdgcn_global_load_lds(
      (__attribute__((address_space(1))) unsigned int*)g,
      (__attribute__((address_space(3))) unsigned int*)l, 16, 0, 0);
}

__device__ __forceinline__ f4v mfma16(s8v a, s8v b, f4v c) {
  return __builtin_amdgcn_mfma_f32_16x16x32_bf16(a, b, c, 0, 0, 0);
}

__device__ __forceinline__ unsigned short f2bfu(float f) {
  union { bf16 h; unsigned short u; } cv;
  cv.h = __float2bfloat16(f);
  return cv.u;
}

// ---------------- prep: hs fp32->bf16 + 8 weight transposes + bias concat ----------------
__global__ __launch_bounds__(256) void prep(
    const float* __restrict__ hs, bf16* __restrict__ hsb,
    const float* __restrict__ bdkv, const float* __restrict__ bdq,
    const float* __restrict__ bkr, const float* __restrict__ bqr,
    float* __restrict__ bcat,
    const float* __restrict__ wdkv, bf16* __restrict__ tdkv,
    const float* __restrict__ wdq,  bf16* __restrict__ tdq,
    const float* __restrict__ wkr,  bf16* __restrict__ tkr,
    const float* __restrict__ wqr,  bf16* __restrict__ tqr,
    const float* __restrict__ wuk,  bf16* __restrict__ tuk,
    const float* __restrict__ wuv,  bf16* __restrict__ tuv,
    const float* __restrict__ wuq,  bf16* __restrict__ tuq,
    const float* __restrict__ wo,   bf16* __restrict__ to_) {
  int bid = blockIdx.x;
  int tid = threadIdx.x;
  if (bid < 4096) {
    int i = (bid * 256 + tid) * 8;
    union { s8v v; unsigned short u[8]; } pk;
#pragma unroll
    for (int j = 0; j < 8; j++) pk.u[j] = f2bfu(hs[i + j]);
    *(s8v*)(hsb + i) = pk.v;
    return;
  }
  if (bid == 4096) {
#pragma unroll
    for (int p = 0; p < 5; p++) {
      int i = tid + p * 256;
      float v;
      if (i < 512)       v = bdkv[i];
      else if (i < 1024) v = bdq[i - 512];
      else if (i < 1152) v = bkr[i - 1024];
      else               v = bqr[i - 1152];
      bcat[i] = v;
    }
    return;
  }
  bid -= 4097;
  const float* src; bf16* dst; int R, C;
  if      (bid < 1024) { src = wdkv; dst = tdkv; R = 2048; C = 512;  }
  else if (bid < 2048) { src = wdq;  dst = tdq;  R = 2048; C = 512;  bid -= 1024; }
  else if (bid < 2304) { src = wkr;  dst = tkr;  R = 2048; C = 128;  bid -= 2048; }
  else if (bid < 2560) { src = wqr;  dst = tqr;  R = 2048; C = 128;  bid -= 2304; }
  else if (bid < 3584) { src = wuk;  dst = tuk;  R = 512;  C = 2048; bid -= 2560; }
  else if (bid < 4608) { src = wuv;  dst = tuv;  R = 512;  C = 2048; bid -= 3584; }
  else if (bid < 5632) { src = wuq;  dst = tuq;  R = 512;  C = 2048; bid -= 4608; }
  else                 { src = wo;   dst = to_;  R = 2048; C = 2048; bid -= 5632; }
  __shared__ float t[32][33];
  int C32 = C >> 5;
  int bx = bid % C32, by = bid / C32;
  int tx = tid & 31, ty = tid >> 5;
  int c0 = bx * 32, r0 = by * 32;
#pragma unroll
  for (int i = 0; i < 32; i += 8)
    t[ty + i][tx] = src[(size_t)(r0 + ty + i) * C + c0 + tx];
  __syncthreads();
#pragma unroll
  for (int i = 0; i < 32; i += 8)
    dst[(size_t)(c0 + ty + i) * R + r0 + tx] = __float2bfloat16(t[tx][ty + i]);
}

// ---------------- rope (both k and q in one launch) ----------------
__global__ void rope_kernel(const bf16* __restrict__ inK, bf16* __restrict__ outK,
                            const bf16* __restrict__ inQ, bf16* __restrict__ outQ) {
  const bf16* in = (blockIdx.y == 0) ? inK : inQ;
  bf16* out = (blockIdx.y == 0) ? outK : outQ;
  int row = blockIdx.x;       // b*2048 + s
  int d = threadIdx.x;        // 0..63
  int pos = row & 2047;
  float x1 = __bfloat162float(in[(size_t)row * 128 + d]);
  float x2 = __bfloat162float(in[(size_t)row * 128 + 64 + d]);
  float inv = exp2f(-(float)d * (13.287712379549449f / 64.0f));  // 10000^(-d/64)
  float ang = (float)pos * inv;
  float sn = sinf(ang), cs = cosf(ang);
  out[(size_t)row * 128 + d]      = __float2bfloat16(x1 * cs - x2 * sn);
  out[(size_t)row * 128 + 64 + d] = __float2bfloat16(x1 * sn + x2 * cs);
}

// ---------------- GEMM: C(MxN) = A(MxK) @ Bt(NxK)^T + bias ----------------
// m97 structure: 128x128 tile, BK=32, 4 waves (2x2), global_load_lds w=16.
template <int MODE>
__global__ __launch_bounds__(256) void gemm_bt(
    const bf16* __restrict__ A, const bf16* __restrict__ A2,
    const bf16* __restrict__ Bt,
    const float* __restrict__ b0, const float* __restrict__ b1,
    const float* __restrict__ b2,
    void* __restrict__ C0, void* __restrict__ C1,
    void* __restrict__ C2, void* __restrict__ C3,
    int M, int N, int K) {
  __shared__ bf16 sA[128 * 32];
  __shared__ bf16 sB[128 * 32];
  const int tid = threadIdx.x, lane = tid & 63, wid = tid >> 6;
  const int l15 = lane & 15, l4 = lane >> 4;
  const int m0 = blockIdx.y * 128, n0 = blockIdx.x * 128;
  const int wm = (wid >> 1) * 64, wn = (wid & 1) * 64;
  f4v acc[4][4] = {};
  const bf16* Ause = (MODE == 2 && n0 >= 4096) ? A2 : A;
  const bf16* gA = Ause + (size_t)m0 * K;
  const bf16* gB = Bt + (size_t)n0 * K;
  const int row = tid >> 2, col = (tid & 3) * 8;
  for (int k0 = 0; k0 < K; k0 += 32) {
    gld16(gA + (size_t)row * K + k0 + col,        sA + tid * 8);
    gld16(gA + (size_t)(row + 64) * K + k0 + col, sA + (tid + 256) * 8);
    gld16(gB + (size_t)row * K + k0 + col,        sB + tid * 8);
    gld16(gB + (size_t)(row + 64) * K + k0 + col, sB + (tid + 256) * 8);
    __syncthreads();
    s8v a[4], b[4];
#pragma unroll
    for (int i = 0; i < 4; i++) a[i] = *(const s8v*)(sA + (wm + i * 16 + l15) * 32 + l4 * 8);
#pragma unroll
    for (int j = 0; j < 4; j++) b[j] = *(const s8v*)(sB + (wn + j * 16 + l15) * 32 + l4 * 8);
#pragma unroll
    for (int i = 0; i < 4; i++)
#pragma unroll
      for (int j = 0; j < 4; j++) acc[i][j] = mfma16(a[i], b[j], acc[i][j]);
    __syncthreads();
  }
  // epilogue. C/D layout: row = l4*4+g, col = l15 (within 16x16 tile)
#pragma unroll
  for (int j = 0; j < 4; j++) {
    const int nb = n0 + wn + j * 16;      // 16-col tile base (uniform per j)
    const int n = nb + l15;
    if (MODE == 3) {
      const float bv = b0[n];
#pragma unroll
      for (int i = 0; i < 4; i++) {
        size_t mb = m0 + wm + i * 16 + l4 * 4;
#pragma unroll
        for (int g = 0; g < 4; g++)
          ((float*)C0)[(mb + g) * (size_t)N + n] = acc[i][j][g] + bv;
      }
    } else if (MODE == 1) {
      const float bv = b0[n];  // 1280-entry concat
      bf16* dst; int stride, nc;
      if (nb < 512)       { dst = (bf16*)C0; stride = 512; nc = n; }
      else if (nb < 1024) { dst = (bf16*)C1; stride = 512; nc = n - 512; }
      else if (nb < 1152) { dst = (bf16*)C2; stride = 128; nc = n - 1024; }
      else                { dst = (bf16*)C3; stride = 128; nc = n - 1152; }
#pragma unroll
      for (int i = 0; i < 4; i++) {
        size_t mb = m0 + wm + i * 16 + l4 * 4;
#pragma unroll
        for (int g = 0; g < 4; g++)
          dst[(mb + g) * (size_t)stride + nc] = __float2bfloat16(acc[i][j][g] + bv);
      }
    } else {  // MODE 2: UK (k_c) | UV (vT) | UQ (q_c)
      if (nb < 2048) {
        const float bv = b0[n];
        bf16* dst = (bf16*)C0;
#pragma unroll
        for (int i = 0; i < 4; i++) {
          size_t mb = m0 + wm + i * 16 + l4 * 4;
#pragma unroll
          for (int g = 0; g < 4; g++)
            dst[(mb + g) * (size_t)2048 + n] = __float2bfloat16(acc[i][j][g] + bv);
        }
      } else if (nb < 4096) {
        const float bv = b1[n - 2048];
        bf16* dst = (bf16*)C1;
        int nn = n - 2048, hh = nn >> 7, dd = nn & 127;
#pragma unroll
        for (int i = 0; i < 4; i++) {
          int m = m0 + wm + i * 16 + l4 * 4;
          int bb = m >> 11, ss = m & 2047;
          unsigned int lo = f2bfu(acc[i][j][0] + bv) | ((unsigned int)f2bfu(acc[i][j][1] + bv) << 16);
          unsigned int hi = f2bfu(acc[i][j][2] + bv) | ((unsigned int)f2bfu(acc[i][j][3] + bv) << 16);
          size_t dstoff = ((size_t)(bb * 16 + hh) * 128 + dd) * 2048 + ss;
          uint2 pk; pk.x = lo; pk.y = hi;
          *reinterpret_cast<uint2*>(dst + dstoff) = pk;
        }
      } else {
        const float bv = b2[n - 4096];
        bf16* dst = (bf16*)C2;
        int nn = n - 4096;
#pragma unroll
        for (int i = 0; i < 4; i++) {
          size_t mb = m0 + wm + i * 16 + l4 * 4;
#pragma unroll
          for (int g = 0; g < 4; g++)
            dst[(mb + g) * (size_t)2048 + nn] = __float2bfloat16(acc[i][j][g] + bv);
        }
      }
    }
  }
}

// ---------------- flash attention (no-max softmax, swapped QK^T, dbuf, BN=64) ----------------
// grid (S/128, B*NH), 512 thr = 8 waves; wave owns 16 q-rows. BN=64 keys/iter,
// 32 iters. LDS: sK/sKr[2] = [dch16][key64][8] 16KB ea, sVT[2] = [kch8][d128][8]
// 16KB ea -> 96KB, 1 block/CU. One barrier/iter; prefetch in flight across the
// whole compute phase. Swapped QK: lane holds P^T[key=m*16+l4*4+g][q=l15];
// PV A-frags (2 key-halves) assembled with 16 ds_bpermute + 8 cndmask.
__global__ __launch_bounds__(512, 2) void flash_attn(
    const bf16* __restrict__ Qc, const bf16* __restrict__ Kc,
    const bf16* __restrict__ Qr, const bf16* __restrict__ Kr,
    const bf16* __restrict__ VT, const int* __restrict__ amask,
    bf16* __restrict__ ctx) {
  const int S = 2048, H = 2048, D = 128;
  __shared__ bf16 sK[2][16 * 64 * 8];
  __shared__ bf16 sKr[2][16 * 64 * 8];
  __shared__ bf16 sVT[2][8 * 128 * 8];

  const int tid = threadIdx.x, lane = tid & 63, wid = tid >> 6;
  const int l15 = lane & 15, l4 = lane >> 4;
  const int qt = blockIdx.x, bh = blockIdx.y;
  const int b = bh >> 4, h = bh & 15;
  const size_t bS = (size_t)b * S;
  const int q0 = qt * 128 + wid * 16;

  // Q fragments in registers (A/B-frag: non-k index = l15 -> q = q0 + l15;
  // k = t*32 + l4*8 + j)
  s8v qcf[4], qrf[4];
  {
    size_t qrow = bS + q0 + l15;
    const bf16* pc = Qc + qrow * H + h * D + l4 * 8;
    const bf16* pr = Qr + qrow * D + l4 * 8;
#pragma unroll
    for (int t = 0; t < 4; t++) {
      qcf[t] = *(const s8v*)(pc + t * 32);
      qrf[t] = *(const s8v*)(pr + t * 32);
    }
  }

  f4v oacc[8] = {};
  float lsum = 0.f;
  const float scl = 0.08838834764831845f;  // 1/sqrt(128)

  // 512 threads x 2 passes fill 1024 slots per buffer type.
  auto stage = [&](int buf, int kv) {
#pragma unroll
    for (int p = 0; p < 2; p++) {
      int idx = tid + p * 512;
      int key = idx & 63, dch = idx >> 6;
      gld16(Kc + (bS + kv + key) * H + h * D + dch * 8, sK[buf] + idx * 8);
      gld16(Kr + (bS + kv + key) * D + dch * 8, sKr[buf] + idx * 8);
      int d = idx & 127, kch = idx >> 7;
      gld16(VT + ((size_t)bh * D + d) * S + kv + kch * 8, sVT[buf] + idx * 8);
    }
  };

  // bpermute source-lane byte addresses (loop-invariant)
  const int ae = ((2 * (l4 & 1)) * 16 + l15) * 4;   // src lane group even
  const int ao = ae + 64;                           // src lane group odd (+16)
  const bool mhi = (l4 >= 2);                       // dest wants upper-m packs

  stage(0, 0);
  for (int it = 0; it < 32; ++it) {
    const int cur = it & 1;
    const int kv0 = it * 64;
    __syncthreads();                       // drains cur's loads; prev reads done
    if (it + 1 < 32) stage(cur ^ 1, (it + 1) * 64);  // prefetch across compute

    // mask per key: key = kv0 + m*16 + l4*4 + g (int4-aligned)
    int4 mv[4];
#pragma unroll
    for (int m = 0; m < 4; m++)
      mv[m] = *(const int4*)(amask + bS + kv0 + m * 16 + l4 * 4);

    // S^T = Kc.Qc^T + Kr.Qr^T (swapped): rows=key (4 tiles of 16), cols=q.
    // t-outer/m-inner: 4 independent acc chains interleaved -> issue-limited.
    f4v sc[4] = {};
    __builtin_amdgcn_s_setprio(1);
#pragma unroll
    for (int t = 0; t < 4; t++)
#pragma unroll
      for (int m = 0; m < 4; m++) {
        s8v kf = *(const s8v*)(sK[cur] + ((t * 4 + l4) * 64 + m * 16 + l15) * 8);
        sc[m] = mfma16(kf, qcf[t], sc[m]);
      }
#pragma unroll
    for (int t = 0; t < 4; t++)
#pragma unroll
      for (int m = 0; m < 4; m++) {
        s8v kf = *(const s8v*)(sKr[cur] + ((t * 4 + l4) * 64 + m * 16 + l15) * 8);
        sc[m] = mfma16(kf, qrf[t], sc[m]);
      }
    __builtin_amdgcn_s_setprio(0);

    // no-max softmax, packed to bf16 pairs: pk[m][w] (w=0: g0|g1, w=1: g2|g3)
    unsigned int pk[4][2];
#pragma unroll
    for (int m = 0; m < 4; m++) {
      float p0 = mv[m].x ? __expf(sc[m][0] * scl) : 0.f;
      float p1 = mv[m].y ? __expf(sc[m][1] * scl) : 0.f;
      float p2 = mv[m].z ? __expf(sc[m][2] * scl) : 0.f;
      float p3 = mv[m].w ? __expf(sc[m][3] * scl) : 0.f;
      lsum += (p0 + p1) + (p2 + p3);
      pk[m][0] = (unsigned int)f2bfu(p0) | ((unsigned int)f2bfu(p1) << 16);
      pk[m][1] = (unsigned int)f2bfu(p2) | ((unsigned int)f2bfu(p3) << 16);
    }

    // assemble PV A-frags in-register, one per 32-key half (8 bperm + 4 sel ea)
    s8v pf[2];
#pragma unroll
    for (int s = 0; s < 2; s++) {
      int a0 = __builtin_amdgcn_ds_bpermute(ae, (int)pk[2 * s][0]);
      int b0 = __builtin_amdgcn_ds_bpermute(ae, (int)pk[2 * s + 1][0]);
      int a1 = __builtin_amdgcn_ds_bpermute(ae, (int)pk[2 * s][1]);
      int b1 = __builtin_amdgcn_ds_bpermute(ae, (int)pk[2 * s + 1][1]);
      int a2 = __builtin_amdgcn_ds_bpermute(ao, (int)pk[2 * s][0]);
      int b2 = __builtin_amdgcn_ds_bpermute(ao, (int)pk[2 * s + 1][0]);
      int a3 = __builtin_amdgcn_ds_bpermute(ao, (int)pk[2 * s][1]);
      int b3 = __builtin_amdgcn_ds_bpermute(ao, (int)pk[2 * s + 1][1]);
      union { int w[4]; s8v v; } u;
      u.w[0] = mhi ? b0 : a0;
      u.w[1] = mhi ? b1 : a1;
      u.w[2] = mhi ? b2 : a2;
      u.w[3] = mhi ? b3 : a3;
      pf[s] = u.v;
    }

    // O += P @ V  (A: q=l15, k=key-in-half=l4*8+j; B: n=d=c*16+l15).
    // pf0 sweep then pf1 sweep: 8 independent chains, dep distance 8.
    __builtin_amdgcn_s_setprio(1);
#pragma unroll
    for (int c = 0; c < 8; c++) {
      s8v vf = *(const s8v*)(sVT[cur] + (l4 * 128 + c * 16 + l15) * 8);
      oacc[c] = mfma16(pf[0], vf, oacc[c]);
    }
#pragma unroll
    for (int c = 0; c < 8; c++) {
      s8v vf = *(const s8v*)(sVT[cur] + ((4 + l4) * 128 + c * 16 + l15) * 8);
      oacc[c] = mfma16(pf[1], vf, oacc[c]);
    }
    __builtin_amdgcn_s_setprio(0);
  }

  // finalize row sums: lsum covers q=l15 (partial over this lane's keys)
  // -> reduce across l4 groups, then redistribute to oacc's q=l4*4+g.
  float inv[4];
  {
    float s = lsum;
    s += __shfl_xor(s, 16, 64);
    s += __shfl_xor(s, 32, 64);
#pragma unroll
    for (int g = 0; g < 4; g++) inv[g] = 1.0f / __shfl(s, l4 * 4 + g, 64);
  }

  // normalize + store ctx (B,S,H). oacc row = q = l4*4 + g, col = d.
#pragma unroll
  for (int c = 0; c < 8; c++) {
#pragma unroll
    for (int g = 0; g < 4; g++) {
      int qrow = q0 + l4 * 4 + g;
      float val = oacc[c][g] * inv[g];
      ctx[(bS + qrow) * H + h * D + c * 16 + l15] = __float2bfloat16(val);
    }
  }
}

// ---------------- launch ----------------
extern "C" void kernel_launch(void* const* d_in, const int* in_sizes, int n_in,
                              void* d_out, int out_size, void* d_ws, size_t ws_size,
                              hipStream_t stream) {
  const float* hs    = (const float*)d_in[0];
  const int*   amask = (const int*)d_in[1];
  const float* W_DKV = (const float*)d_in[2];  const float* b_DKV = (const float*)d_in[3];
  const float* W_DQ  = (const float*)d_in[4];  const float* b_DQ  = (const float*)d_in[5];
  const float* W_UK  = (const float*)d_in[6];  const float* b_UK  = (const float*)d_in[7];
  const float* W_UV  = (const float*)d_in[8];  const float* b_UV  = (const float*)d_in[9];
  const float* W_UQ  = (const float*)d_in[10]; const float* b_UQ  = (const float*)d_in[11];
  const float* W_KR  = (const float*)d_in[12]; const float* b_KR  = (const float*)d_in[13];
  const float* W_QR  = (const float*)d_in[14]; const float* b_QR  = (const float*)d_in[15];
  const float* W_O   = (const float*)d_in[16]; const float* b_O   = (const float*)d_in[17];

  char* wsb = (char*)d_ws;
  size_t off = 0;
  auto allocB = [&](size_t bytes) {
    void* p = wsb + off; off = (off + bytes + 255) & ~(size_t)255; return p;
  };
  float* bcat  = (float*)allocB(1280 * 4);
  bf16* hsb    = (bf16*)allocB((size_t)4096 * 2048 * 2);
  bf16* wt_dkv = (bf16*)allocB((size_t)512 * 2048 * 2);
  bf16* wt_dq  = (bf16*)allocB((size_t)512 * 2048 * 2);
  bf16* wt_kr  = (bf16*)allocB((size_t)128 * 2048 * 2);
  bf16* wt_qr  = (bf16*)allocB((size_t)128 * 2048 * 2);
  // wt_uk|wt_uv|wt_uq MUST stay contiguous (single Bt for the merged GEMM):
  bf16* wt_uk  = (bf16*)allocB((size_t)2048 * 512 * 2);
  bf16* wt_uv  = (bf16*)allocB((size_t)2048 * 512 * 2);
  bf16* wt_uq  = (bf16*)allocB((size_t)2048 * 512 * 2);
  bf16* wt_o   = (bf16*)allocB((size_t)2048 * 2048 * 2);
  bf16* c_kv   = (bf16*)allocB((size_t)4096 * 512 * 2);
  bf16* c_q    = (bf16*)allocB((size_t)4096 * 512 * 2);
  bf16* krl    = (bf16*)allocB((size_t)4096 * 128 * 2);
  bf16* qrl    = (bf16*)allocB((size_t)4096 * 128 * 2);
  bf16* k_r    = (bf16*)allocB((size_t)4096 * 128 * 2);
  bf16* q_r    = (bf16*)allocB((size_t)4096 * 128 * 2);
  bf16* k_c    = (bf16*)allocB((size_t)4096 * 2048 * 2);
  bf16* q_c    = (bf16*)allocB((size_t)4096 * 2048 * 2);
  bf16* vT     = (bf16*)allocB((size_t)4096 * 2048 * 2);
  bf16* ctx    = (bf16*)allocB((size_t)4096 * 2048 * 2);
  (void)wt_uv; (void)wt_uq;

  // one-shot ingest: 4096 hs-convert + 1 bias-concat + 9728 transpose tiles
  prep<<<13825, 256, 0, stream>>>(hs, hsb,
      b_DKV, b_DQ, b_KR, b_QR, bcat,
      W_DKV, wt_dkv, W_DQ, wt_dq, W_KR, wt_kr, W_QR, wt_qr,
      W_UK, wt_uk, W_UV, wt_uv, W_UQ, wt_uq, W_O, wt_o);

  // fused projections: N = 512|512|128|128 = 1280, K = 2048
  gemm_bt<1><<<dim3(10, 32), 256, 0, stream>>>(
      hsb, nullptr, wt_dkv, bcat, nullptr, nullptr,
      c_kv, c_q, krl, qrl, 4096, 1280, 2048);
  rope_kernel<<<dim3(4096, 2), 64, 0, stream>>>(krl, k_r, qrl, q_r);

  // merged UK|UV|UQ: N = 2048*3 = 6144, K = 512 (A = c_kv for n<4096, c_q above)
  gemm_bt<2><<<dim3(48, 32), 256, 0, stream>>>(
      c_kv, c_q, wt_uk, b_UK, b_UV, b_UQ,
      k_c, vT, q_c, nullptr, 4096, 6144, 512);

  // attention: grid (2048/128, 32) = 512 blocks x 512 thr, 1 block/CU (96KB LDS)
  flash_attn<<<dim3(16, 32), 512, 0, stream>>>(q_c, k_c, q_r, k_r, vT, amask, ctx);

  // output projection (fp32 out)
  gemm_bt<3><<<dim3(16, 32), 256, 0, stream>>>(
      ctx, nullptr, wt_o, b_O, nullptr, nullptr,
      d_out, nullptr, nullptr, nullptr, 4096, 2048, 2048);
}

// Round 5
// 490.283 us; speedup vs baseline: 1.0309x; 1.0309x over previous
//
#include <hip/hip_runtime.h>
#include <hip/hip_bf16.h>
#include <stdint.h>

// MLA forward: B=2,S=2048,H=2048,NH=16,D=128,LAT=512. Inputs fp32 (R3-proven).
// R14: flash = R11 (best: 176us; 4 waves x 32 q, BN=32, 2 blk/CU) minus the
// sKr pipeline: Kr fragments read DIRECT from global. Kr is head-shared (16
// heads x 16 q-blocks read the same 1MB -> L2/L1-hot; 4 waves read identical
// rows -> L1 broadcast). Deletes 8 staging wave-ops + 32 kf b128 reads per
// block-iter: LDS pipe (the 64%-busy critical resource per R11 busy-sum) drops
// ~27%. krf issued FIRST after barrier (oldest vmcnt -> stage stays in flight),
// latency hides under Kc-MFMA phase. launch_bounds(256,2): no R10 spill trap.
// R12 (occupancy) and R13 (BN=64) both falsified -> structure stays R11.
typedef __hip_bfloat16 bf16;
typedef __attribute__((ext_vector_type(8))) short s8v;   // 8 x bf16 (4 VGPRs)
typedef __attribute__((ext_vector_type(4))) float f4v;   // MFMA 16x16 accum

__device__ __forceinline__ void gld16(const bf16* g, bf16* l) {
  __builtin_amdgcn_global_load_lds(
      (__attribute__((address_space(1))) unsigned int*)g,
      (__attribute__((address_space(3))) unsigned int*)l, 16, 0, 0);
}

__device__ __forceinline__ f4v mfma16(s8v a, s8v b, f4v c) {
  return __builtin_amdgcn_mfma_f32_16x16x32_bf16(a, b, c, 0, 0, 0);
}

__device__ __forceinline__ unsigned short f2bfu(float f) {
  union { bf16 h; unsigned short u; } cv;
  cv.h = __float2bfloat16(f);
  return cv.u;
}

// ---------------- prep: hs fp32->bf16 + 8 weight transposes + bias concat ----------------
__global__ __launch_bounds__(256) void prep(
    const float* __restrict__ hs, bf16* __restrict__ hsb,
    const float* __restrict__ bdkv, const float* __restrict__ bdq,
    const float* __restrict__ bkr, const float* __restrict__ bqr,
    float* __restrict__ bcat,
    const float* __restrict__ wdkv, bf16* __restrict__ tdkv,
    const float* __restrict__ wdq,  bf16* __restrict__ tdq,
    const float* __restrict__ wkr,  bf16* __restrict__ tkr,
    const float* __restrict__ wqr,  bf16* __restrict__ tqr,
    const float* __restrict__ wuk,  bf16* __restrict__ tuk,
    const float* __restrict__ wuv,  bf16* __restrict__ tuv,
    const float* __restrict__ wuq,  bf16* __restrict__ tuq,
    const float* __restrict__ wo,   bf16* __restrict__ to_) {
  int bid = blockIdx.x;
  int tid = threadIdx.x;
  if (bid < 4096) {
    int i = (bid * 256 + tid) * 8;
    union { s8v v; unsigned short u[8]; } pk;
#pragma unroll
    for (int j = 0; j < 8; j++) pk.u[j] = f2bfu(hs[i + j]);
    *(s8v*)(hsb + i) = pk.v;
    return;
  }
  if (bid == 4096) {
#pragma unroll
    for (int p = 0; p < 5; p++) {
      int i = tid + p * 256;
      float v;
      if (i < 512)       v = bdkv[i];
      else if (i < 1024) v = bdq[i - 512];
      else if (i < 1152) v = bkr[i - 1024];
      else               v = bqr[i - 1152];
      bcat[i] = v;
    }
    return;
  }
  bid -= 4097;
  const float* src; bf16* dst; int R, C;
  if      (bid < 1024) { src = wdkv; dst = tdkv; R = 2048; C = 512;  }
  else if (bid < 2048) { src = wdq;  dst = tdq;  R = 2048; C = 512;  bid -= 1024; }
  else if (bid < 2304) { src = wkr;  dst = tkr;  R = 2048; C = 128;  bid -= 2048; }
  else if (bid < 2560) { src = wqr;  dst = tqr;  R = 2048; C = 128;  bid -= 2304; }
  else if (bid < 3584) { src = wuk;  dst = tuk;  R = 512;  C = 2048; bid -= 2560; }
  else if (bid < 4608) { src = wuv;  dst = tuv;  R = 512;  C = 2048; bid -= 3584; }
  else if (bid < 5632) { src = wuq;  dst = tuq;  R = 512;  C = 2048; bid -= 4608; }
  else                 { src = wo;   dst = to_;  R = 2048; C = 2048; bid -= 5632; }
  __shared__ float t[32][33];
  int C32 = C >> 5;
  int bx = bid % C32, by = bid / C32;
  int tx = tid & 31, ty = tid >> 5;
  int c0 = bx * 32, r0 = by * 32;
#pragma unroll
  for (int i = 0; i < 32; i += 8)
    t[ty + i][tx] = src[(size_t)(r0 + ty + i) * C + c0 + tx];
  __syncthreads();
#pragma unroll
  for (int i = 0; i < 32; i += 8)
    dst[(size_t)(c0 + ty + i) * R + r0 + tx] = __float2bfloat16(t[tx][ty + i]);
}

// ---------------- rope (both k and q in one launch) ----------------
__global__ void rope_kernel(const bf16* __restrict__ inK, bf16* __restrict__ outK,
                            const bf16* __restrict__ inQ, bf16* __restrict__ outQ) {
  const bf16* in = (blockIdx.y == 0) ? inK : inQ;
  bf16* out = (blockIdx.y == 0) ? outK : outQ;
  int row = blockIdx.x;       // b*2048 + s
  int d = threadIdx.x;        // 0..63
  int pos = row & 2047;
  float x1 = __bfloat162float(in[(size_t)row * 128 + d]);
  float x2 = __bfloat162float(in[(size_t)row * 128 + 64 + d]);
  float inv = exp2f(-(float)d * (13.287712379549449f / 64.0f));  // 10000^(-d/64)
  float ang = (float)pos * inv;
  float sn = sinf(ang), cs = cosf(ang);
  out[(size_t)row * 128 + d]      = __float2bfloat16(x1 * cs - x2 * sn);
  out[(size_t)row * 128 + 64 + d] = __float2bfloat16(x1 * sn + x2 * cs);
}

// ---------------- GEMM: C(MxN) = A(MxK) @ Bt(NxK)^T + bias ----------------
// m97 structure: 128x128 tile, BK=32, 4 waves (2x2), global_load_lds w=16.
template <int MODE>
__global__ __launch_bounds__(256) void gemm_bt(
    const bf16* __restrict__ A, const bf16* __restrict__ A2,
    const bf16* __restrict__ Bt,
    const float* __restrict__ b0, const float* __restrict__ b1,
    const float* __restrict__ b2,
    void* __restrict__ C0, void* __restrict__ C1,
    void* __restrict__ C2, void* __restrict__ C3,
    int M, int N, int K) {
  __shared__ bf16 sA[128 * 32];
  __shared__ bf16 sB[128 * 32];
  const int tid = threadIdx.x, lane = tid & 63, wid = tid >> 6;
  const int l15 = lane & 15, l4 = lane >> 4;
  const int m0 = blockIdx.y * 128, n0 = blockIdx.x * 128;
  const int wm = (wid >> 1) * 64, wn = (wid & 1) * 64;
  f4v acc[4][4] = {};
  const bf16* Ause = (MODE == 2 && n0 >= 4096) ? A2 : A;
  const bf16* gA = Ause + (size_t)m0 * K;
  const bf16* gB = Bt + (size_t)n0 * K;
  const int row = tid >> 2, col = (tid & 3) * 8;
  for (int k0 = 0; k0 < K; k0 += 32) {
    gld16(gA + (size_t)row * K + k0 + col,        sA + tid * 8);
    gld16(gA + (size_t)(row + 64) * K + k0 + col, sA + (tid + 256) * 8);
    gld16(gB + (size_t)row * K + k0 + col,        sB + tid * 8);
    gld16(gB + (size_t)(row + 64) * K + k0 + col, sB + (tid + 256) * 8);
    __syncthreads();
    s8v a[4], b[4];
#pragma unroll
    for (int i = 0; i < 4; i++) a[i] = *(const s8v*)(sA + (wm + i * 16 + l15) * 32 + l4 * 8);
#pragma unroll
    for (int j = 0; j < 4; j++) b[j] = *(const s8v*)(sB + (wn + j * 16 + l15) * 32 + l4 * 8);
#pragma unroll
    for (int i = 0; i < 4; i++)
#pragma unroll
      for (int j = 0; j < 4; j++) acc[i][j] = mfma16(a[i], b[j], acc[i][j]);
    __syncthreads();
  }
  // epilogue. C/D layout: row = l4*4+g, col = l15 (within 16x16 tile)
#pragma unroll
  for (int j = 0; j < 4; j++) {
    const int nb = n0 + wn + j * 16;      // 16-col tile base (uniform per j)
    const int n = nb + l15;
    if (MODE == 3) {
      const float bv = b0[n];
#pragma unroll
      for (int i = 0; i < 4; i++) {
        size_t mb = m0 + wm + i * 16 + l4 * 4;
#pragma unroll
        for (int g = 0; g < 4; g++)
          ((float*)C0)[(mb + g) * (size_t)N + n] = acc[i][j][g] + bv;
      }
    } else if (MODE == 1) {
      const float bv = b0[n];  // 1280-entry concat
      bf16* dst; int stride, nc;
      if (nb < 512)       { dst = (bf16*)C0; stride = 512; nc = n; }
      else if (nb < 1024) { dst = (bf16*)C1; stride = 512; nc = n - 512; }
      else if (nb < 1152) { dst = (bf16*)C2; stride = 128; nc = n - 1024; }
      else                { dst = (bf16*)C3; stride = 128; nc = n - 1152; }
#pragma unroll
      for (int i = 0; i < 4; i++) {
        size_t mb = m0 + wm + i * 16 + l4 * 4;
#pragma unroll
        for (int g = 0; g < 4; g++)
          dst[(mb + g) * (size_t)stride + nc] = __float2bfloat16(acc[i][j][g] + bv);
      }
    } else {  // MODE 2: UK (k_c) | UV (vT) | UQ (q_c)
      if (nb < 2048) {
        const float bv = b0[n];
        bf16* dst = (bf16*)C0;
#pragma unroll
        for (int i = 0; i < 4; i++) {
          size_t mb = m0 + wm + i * 16 + l4 * 4;
#pragma unroll
          for (int g = 0; g < 4; g++)
            dst[(mb + g) * (size_t)2048 + n] = __float2bfloat16(acc[i][j][g] + bv);
        }
      } else if (nb < 4096) {
        const float bv = b1[n - 2048];
        bf16* dst = (bf16*)C1;
        int nn = n - 2048, hh = nn >> 7, dd = nn & 127;
#pragma unroll
        for (int i = 0; i < 4; i++) {
          int m = m0 + wm + i * 16 + l4 * 4;
          int bb = m >> 11, ss = m & 2047;
          unsigned int lo = f2bfu(acc[i][j][0] + bv) | ((unsigned int)f2bfu(acc[i][j][1] + bv) << 16);
          unsigned int hi = f2bfu(acc[i][j][2] + bv) | ((unsigned int)f2bfu(acc[i][j][3] + bv) << 16);
          size_t dstoff = ((size_t)(bb * 16 + hh) * 128 + dd) * 2048 + ss;
          uint2 pk; pk.x = lo; pk.y = hi;
          *reinterpret_cast<uint2*>(dst + dstoff) = pk;
        }
      } else {
        const float bv = b2[n - 4096];
        bf16* dst = (bf16*)C2;
        int nn = n - 4096;
#pragma unroll
        for (int i = 0; i < 4; i++) {
          size_t mb = m0 + wm + i * 16 + l4 * 4;
#pragma unroll
          for (int g = 0; g < 4; g++)
            dst[(mb + g) * (size_t)2048 + nn] = __float2bfloat16(acc[i][j][g] + bv);
        }
      }
    }
  }
}

// ---------------- flash attention (no-max softmax, swapped QK^T, dbuf) ----------------
// grid (S/128, B*NH), 256 thr (4 waves; wave owns 32 q-rows). BN=32 keys/iter.
// LDS: sK/sVT[2] 8KB each -> 32KB, 2 blocks/CU. One barrier/iter; prefetch in
// flight across compute. Kr NOT staged: krf[2][4] A-frags read direct from
// global (L2/L1-hot; issued first after barrier so their vmcnt wait leaves the
// stage() prefetch in flight; latency hides under the Kc-MFMA phase).
// Swapped QK: lane holds P^T[key=m*16+l4*4+g][q=r*16+l15]; PV A-frags
// assembled with 16 ds_bpermute + 8 cndmask.
__global__ __launch_bounds__(256, 2) void flash_attn(
    const bf16* __restrict__ Qc, const bf16* __restrict__ Kc,
    const bf16* __restrict__ Qr, const bf16* __restrict__ Kr,
    const bf16* __restrict__ VT, const int* __restrict__ amask,
    bf16* __restrict__ ctx) {
  const int S = 2048, H = 2048, D = 128;
  __shared__ bf16 sK[2][16 * 32 * 8];
  __shared__ bf16 sVT[2][4 * 128 * 8];

  const int tid = threadIdx.x, lane = tid & 63, wid = tid >> 6;
  const int l15 = lane & 15, l4 = lane >> 4;
  const int qt = blockIdx.x, bh = blockIdx.y;
  const int b = bh >> 4, h = bh & 15;
  const size_t bS = (size_t)b * S;
  const int q0 = qt * 128 + wid * 32;

  // Q fragments in registers. A/B-frag layout identical for 16x16x32:
  // non-k index = l15 -> q = q0 + r*16 + l15; k = t*32 + l4*8 + j.
  s8v qcf[2][4], qrf[2][4];
#pragma unroll
  for (int r = 0; r < 2; r++) {
    size_t qrow = bS + q0 + r * 16 + l15;
    const bf16* pc = Qc + qrow * H + h * D + l4 * 8;
    const bf16* pr = Qr + qrow * D + l4 * 8;
#pragma unroll
    for (int t = 0; t < 4; t++) {
      qcf[r][t] = *(const s8v*)(pc + t * 32);
      qrf[r][t] = *(const s8v*)(pr + t * 32);
    }
  }

  f4v oacc[2][8] = {};
  float lsum[2] = {};
  const float scl = 0.08838834764831845f;  // 1/sqrt(128)

  auto stage = [&](int buf, int kv) {
#pragma unroll
    for (int p = 0; p < 2; p++) {
      int idx = tid + p * 256;
      int key = (idx & 31), dch = (idx >> 5);
      gld16(Kc + (bS + kv + key) * H + h * D + dch * 8, sK[buf] + idx * 8);
      int d = (idx & 127), kch = (idx >> 7);
      gld16(VT + ((size_t)bh * D + d) * S + kv + kch * 8, sVT[buf] + idx * 8);
    }
  };

  // Kr A-frag base: row = bS + kv0 + m*16 + l15, cols (t*4+l4)*8 .. +7
  const bf16* krbase = Kr + (bS + l15) * (size_t)D + l4 * 8;

  // bpermute source-lane byte addresses (loop-invariant)
  const int ae = ((2 * (l4 & 1)) * 16 + l15) * 4;   // src lane group even
  const int ao = ae + 64;                           // src lane group odd (+16)
  const bool mhi = (l4 >= 2);                       // dest wants m=1 packs

  stage(0, 0);
  for (int it = 0; it < 64; ++it) {
    const int cur = it & 1;
    const int kv0 = it * 32;
    __syncthreads();                       // drains cur's loads; prev reads done

    // krf loads FIRST (oldest in vmcnt queue -> waiting for them leaves the
    // stage() prefetch in flight). L2/L1-hot (head-shared, wave-shared rows).
    s8v krf[2][4];
#pragma unroll
    for (int m = 0; m < 2; m++)
#pragma unroll
      for (int t = 0; t < 4; t++)
        krf[m][t] = *(const s8v*)(krbase + (size_t)(kv0 + m * 16) * D + t * 32);

    if (it + 1 < 64) stage(cur ^ 1, (it + 1) * 32);  // prefetch across compute

    // mask per key: key = kv0 + m*16 + l4*4 + g (int4-aligned)
    int4 mv[2];
#pragma unroll
    for (int m = 0; m < 2; m++)
      mv[m] = *(const int4*)(amask + bS + kv0 + m * 16 + l4 * 4);

    // S^T = Kc.Qc^T + Kr.Qr^T (swapped): rows=key, cols=q.
    // Kc first (LDS, ready post-barrier) -> krf global latency hides under it.
    f4v sc[2][2] = {};   // [m: key tile][r: q tile]
    __builtin_amdgcn_s_setprio(1);
#pragma unroll
    for (int m = 0; m < 2; m++)
#pragma unroll
      for (int t = 0; t < 4; t++) {
        s8v kf = *(const s8v*)(sK[cur] + ((t * 4 + l4) * 32 + m * 16 + l15) * 8);
        sc[m][0] = mfma16(kf, qcf[0][t], sc[m][0]);
        sc[m][1] = mfma16(kf, qcf[1][t], sc[m][1]);
      }
#pragma unroll
    for (int m = 0; m < 2; m++)
#pragma unroll
      for (int t = 0; t < 4; t++) {
        sc[m][0] = mfma16(krf[m][t], qrf[0][t], sc[m][0]);
        sc[m][1] = mfma16(krf[m][t], qrf[1][t], sc[m][1]);
      }
    __builtin_amdgcn_s_setprio(0);

    // no-max softmax, packed to bf16 pairs: pk[r][m][w] (w=0: g0|g1, w=1: g2|g3)
    unsigned int pk[2][2][2];
#pragma unroll
    for (int m = 0; m < 2; m++)
#pragma unroll
      for (int r = 0; r < 2; r++) {
        float p0 = mv[m].x ? __expf(sc[m][r][0] * scl) : 0.f;
        float p1 = mv[m].y ? __expf(sc[m][r][1] * scl) : 0.f;
        float p2 = mv[m].z ? __expf(sc[m][r][2] * scl) : 0.f;
        float p3 = mv[m].w ? __expf(sc[m][r][3] * scl) : 0.f;
        lsum[r] += (p0 + p1) + (p2 + p3);
        pk[r][m][0] = (unsigned int)f2bfu(p0) | ((unsigned int)f2bfu(p1) << 16);
        pk[r][m][1] = (unsigned int)f2bfu(p2) | ((unsigned int)f2bfu(p3) << 16);
      }

    // assemble PV A-frags in-register (16 bpermute + 8 select)
    s8v pf[2];
#pragma unroll
    for (int r = 0; r < 2; r++) {
      int a0 = __builtin_amdgcn_ds_bpermute(ae, (int)pk[r][0][0]);
      int b0 = __builtin_amdgcn_ds_bpermute(ae, (int)pk[r][1][0]);
      int a1 = __builtin_amdgcn_ds_bpermute(ae, (int)pk[r][0][1]);
      int b1 = __builtin_amdgcn_ds_bpermute(ae, (int)pk[r][1][1]);
      int a2 = __builtin_amdgcn_ds_bpermute(ao, (int)pk[r][0][0]);
      int b2 = __builtin_amdgcn_ds_bpermute(ao, (int)pk[r][1][0]);
      int a3 = __builtin_amdgcn_ds_bpermute(ao, (int)pk[r][0][1]);
      int b3 = __builtin_amdgcn_ds_bpermute(ao, (int)pk[r][1][1]);
      union { int w[4]; s8v v; } u;
      u.w[0] = mhi ? b0 : a0;
      u.w[1] = mhi ? b1 : a1;
      u.w[2] = mhi ? b2 : a2;
      u.w[3] = mhi ? b3 : a3;
      pf[r] = u.v;
    }

    // O += P @ V  (A: q=l15, k=key=l4*8+j; B: n=d=c*16+l15)
    __builtin_amdgcn_s_setprio(1);
#pragma unroll
    for (int c = 0; c < 8; c++) {
      s8v vf = *(const s8v*)(sVT[cur] + (l4 * 128 + c * 16 + l15) * 8);
      oacc[0][c] = mfma16(pf[0], vf, oacc[0][c]);
      oacc[1][c] = mfma16(pf[1], vf, oacc[1][c]);
    }
    __builtin_amdgcn_s_setprio(0);
  }

  // finalize row sums: lsum[r] covers q=r*16+l15 (partial over this lane's
  // keys) -> reduce across l4 groups, then redistribute to oacc's q=l4*4+g.
  float inv[2][4];
#pragma unroll
  for (int r = 0; r < 2; r++) {
    float s = lsum[r];
    s += __shfl_xor(s, 16, 64);
    s += __shfl_xor(s, 32, 64);
#pragma unroll
    for (int g = 0; g < 4; g++) inv[r][g] = 1.0f / __shfl(s, l4 * 4 + g, 64);
  }

  // normalize + store ctx (B,S,H). oacc row = q = r*16 + l4*4 + g, col = d.
#pragma unroll
  for (int r = 0; r < 2; r++) {
#pragma unroll
    for (int c = 0; c < 8; c++) {
#pragma unroll
      for (int g = 0; g < 4; g++) {
        int qrow = q0 + r * 16 + l4 * 4 + g;
        float val = oacc[r][c][g] * inv[r][g];
        ctx[(bS + qrow) * H + h * D + c * 16 + l15] = __float2bfloat16(val);
      }
    }
  }
}

// ---------------- launch ----------------
extern "C" void kernel_launch(void* const* d_in, const int* in_sizes, int n_in,
                              void* d_out, int out_size, void* d_ws, size_t ws_size,
                              hipStream_t stream) {
  const float* hs    = (const float*)d_in[0];
  const int*   amask = (const int*)d_in[1];
  const float* W_DKV = (const float*)d_in[2];  const float* b_DKV = (const float*)d_in[3];
  const float* W_DQ  = (const float*)d_in[4];  const float* b_DQ  = (const float*)d_in[5];
  const float* W_UK  = (const float*)d_in[6];  const float* b_UK  = (const float*)d_in[7];
  const float* W_UV  = (const float*)d_in[8];  const float* b_UV  = (const float*)d_in[9];
  const float* W_UQ  = (const float*)d_in[10]; const float* b_UQ  = (const float*)d_in[11];
  const float* W_KR  = (const float*)d_in[12]; const float* b_KR  = (const float*)d_in[13];
  const float* W_QR  = (const float*)d_in[14]; const float* b_QR  = (const float*)d_in[15];
  const float* W_O   = (const float*)d_in[16]; const float* b_O   = (const float*)d_in[17];

  char* wsb = (char*)d_ws;
  size_t off = 0;
  auto allocB = [&](size_t bytes) {
    void* p = wsb + off; off = (off + bytes + 255) & ~(size_t)255; return p;
  };
  float* bcat  = (float*)allocB(1280 * 4);
  bf16* hsb    = (bf16*)allocB((size_t)4096 * 2048 * 2);
  bf16* wt_dkv = (bf16*)allocB((size_t)512 * 2048 * 2);
  bf16* wt_dq  = (bf16*)allocB((size_t)512 * 2048 * 2);
  bf16* wt_kr  = (bf16*)allocB((size_t)128 * 2048 * 2);
  bf16* wt_qr  = (bf16*)allocB((size_t)128 * 2048 * 2);
  // wt_uk|wt_uv|wt_uq MUST stay contiguous (single Bt for the merged GEMM):
  bf16* wt_uk  = (bf16*)allocB((size_t)2048 * 512 * 2);
  bf16* wt_uv  = (bf16*)allocB((size_t)2048 * 512 * 2);
  bf16* wt_uq  = (bf16*)allocB((size_t)2048 * 512 * 2);
  bf16* wt_o   = (bf16*)allocB((size_t)2048 * 2048 * 2);
  bf16* c_kv   = (bf16*)allocB((size_t)4096 * 512 * 2);
  bf16* c_q    = (bf16*)allocB((size_t)4096 * 512 * 2);
  bf16* krl    = (bf16*)allocB((size_t)4096 * 128 * 2);
  bf16* qrl    = (bf16*)allocB((size_t)4096 * 128 * 2);
  bf16* k_r    = (bf16*)allocB((size_t)4096 * 128 * 2);
  bf16* q_r    = (bf16*)allocB((size_t)4096 * 128 * 2);
  bf16* k_c    = (bf16*)allocB((size_t)4096 * 2048 * 2);
  bf16* q_c    = (bf16*)allocB((size_t)4096 * 2048 * 2);
  bf16* vT     = (bf16*)allocB((size_t)4096 * 2048 * 2);
  bf16* ctx    = (bf16*)allocB((size_t)4096 * 2048 * 2);
  (void)wt_uv; (void)wt_uq;

  // one-shot ingest: 4096 hs-convert + 1 bias-concat + 9728 transpose tiles
  prep<<<13825, 256, 0, stream>>>(hs, hsb,
      b_DKV, b_DQ, b_KR, b_QR, bcat,
      W_DKV, wt_dkv, W_DQ, wt_dq, W_KR, wt_kr, W_QR, wt_qr,
      W_UK, wt_uk, W_UV, wt_uv, W_UQ, wt_uq, W_O, wt_o);

  // fused projections: N = 512|512|128|128 = 1280, K = 2048
  gemm_bt<1><<<dim3(10, 32), 256, 0, stream>>>(
      hsb, nullptr, wt_dkv, bcat, nullptr, nullptr,
      c_kv, c_q, krl, qrl, 4096, 1280, 2048);
  rope_kernel<<<dim3(4096, 2), 64, 0, stream>>>(krl, k_r, qrl, q_r);

  // merged UK|UV|UQ: N = 2048*3 = 6144, K = 512 (A = c_kv for n<4096, c_q above)
  gemm_bt<2><<<dim3(48, 32), 256, 0, stream>>>(
      c_kv, c_q, wt_uk, b_UK, b_UV, b_UQ,
      k_c, vT, q_c, nullptr, 4096, 6144, 512);

  // attention: grid (2048/128, 32) = 512 blocks, 2 blocks/CU (32KB LDS)
  flash_attn<<<dim3(16, 32), 256, 0, stream>>>(q_c, k_c, q_r, k_r, vT, amask, ctx);

  // output projection (fp32 out)
  gemm_bt<3><<<dim3(16, 32), 256, 0, stream>>>(
      ctx, nullptr, wt_o, b_O, nullptr, nullptr,
      d_out, nullptr, nullptr, nullptr, 4096, 2048, 2048);
}

// Round 6
// 465.795 us; speedup vs baseline: 1.0851x; 1.0526x over previous
//
#include <hip/hip_runtime.h>
#include <hip/hip_bf16.h>
#include <stdint.h>

// MLA forward: B=2,S=2048,H=2048,NH=16,D=128,LAT=512. Inputs fp32 (R3-proven).
// R15: flash rebuilt on 32x32x16 MFMAs (m214 lesson: the 16x16 plateau is
// structural). Keeps ALL R11-proven structure: 4 waves x 32 q, BN=32, staged
// sK/sKr/sVT dbuf, 1 barrier/iter, swapped QK, no-max softmax. Per wave-iter:
// 24 MFMA (was 48, same FLOP), 4 ds_bpermute (was 16; they were the 4.19M
// conflict cycles), P exchange = lane^32 only. Two QK accumulators (Kc/Kr)
// keep dep-chain ILP=2. R12 occupancy / R13 BN=64 / R14 Kr-global all
// falsified -> reverted.
typedef __hip_bfloat16 bf16;
typedef __attribute__((ext_vector_type(8))) short s8v;    // 8 x bf16 (4 VGPRs)
typedef __attribute__((ext_vector_type(4))) float f4v;    // 16x16 accum
typedef __attribute__((ext_vector_type(16))) float f16v;  // 32x32 accum

__device__ __forceinline__ void gld16(const bf16* g, bf16* l) {
  __builtin_amdgcn_global_load_lds(
      (__attribute__((address_space(1))) unsigned int*)g,
      (__attribute__((address_space(3))) unsigned int*)l, 16, 0, 0);
}

__device__ __forceinline__ f4v mfma16(s8v a, s8v b, f4v c) {
  return __builtin_amdgcn_mfma_f32_16x16x32_bf16(a, b, c, 0, 0, 0);
}

__device__ __forceinline__ f16v mfma32(s8v a, s8v b, f16v c) {
  return __builtin_amdgcn_mfma_f32_32x32x16_bf16(a, b, c, 0, 0, 0);
}

__device__ __forceinline__ unsigned short f2bfu(float f) {
  union { bf16 h; unsigned short u; } cv;
  cv.h = __float2bfloat16(f);
  return cv.u;
}

// ---------------- prep: hs fp32->bf16 + 8 weight transposes + bias concat ----------------
__global__ __launch_bounds__(256) void prep(
    const float* __restrict__ hs, bf16* __restrict__ hsb,
    const float* __restrict__ bdkv, const float* __restrict__ bdq,
    const float* __restrict__ bkr, const float* __restrict__ bqr,
    float* __restrict__ bcat,
    const float* __restrict__ wdkv, bf16* __restrict__ tdkv,
    const float* __restrict__ wdq,  bf16* __restrict__ tdq,
    const float* __restrict__ wkr,  bf16* __restrict__ tkr,
    const float* __restrict__ wqr,  bf16* __restrict__ tqr,
    const float* __restrict__ wuk,  bf16* __restrict__ tuk,
    const float* __restrict__ wuv,  bf16* __restrict__ tuv,
    const float* __restrict__ wuq,  bf16* __restrict__ tuq,
    const float* __restrict__ wo,   bf16* __restrict__ to_) {
  int bid = blockIdx.x;
  int tid = threadIdx.x;
  if (bid < 4096) {
    int i = (bid * 256 + tid) * 8;
    union { s8v v; unsigned short u[8]; } pk;
#pragma unroll
    for (int j = 0; j < 8; j++) pk.u[j] = f2bfu(hs[i + j]);
    *(s8v*)(hsb + i) = pk.v;
    return;
  }
  if (bid == 4096) {
#pragma unroll
    for (int p = 0; p < 5; p++) {
      int i = tid + p * 256;
      float v;
      if (i < 512)       v = bdkv[i];
      else if (i < 1024) v = bdq[i - 512];
      else if (i < 1152) v = bkr[i - 1024];
      else               v = bqr[i - 1152];
      bcat[i] = v;
    }
    return;
  }
  bid -= 4097;
  const float* src; bf16* dst; int R, C;
  if      (bid < 1024) { src = wdkv; dst = tdkv; R = 2048; C = 512;  }
  else if (bid < 2048) { src = wdq;  dst = tdq;  R = 2048; C = 512;  bid -= 1024; }
  else if (bid < 2304) { src = wkr;  dst = tkr;  R = 2048; C = 128;  bid -= 2048; }
  else if (bid < 2560) { src = wqr;  dst = tqr;  R = 2048; C = 128;  bid -= 2304; }
  else if (bid < 3584) { src = wuk;  dst = tuk;  R = 512;  C = 2048; bid -= 2560; }
  else if (bid < 4608) { src = wuv;  dst = tuv;  R = 512;  C = 2048; bid -= 3584; }
  else if (bid < 5632) { src = wuq;  dst = tuq;  R = 512;  C = 2048; bid -= 4608; }
  else                 { src = wo;   dst = to_;  R = 2048; C = 2048; bid -= 5632; }
  __shared__ float t[32][33];
  int C32 = C >> 5;
  int bx = bid % C32, by = bid / C32;
  int tx = tid & 31, ty = tid >> 5;
  int c0 = bx * 32, r0 = by * 32;
#pragma unroll
  for (int i = 0; i < 32; i += 8)
    t[ty + i][tx] = src[(size_t)(r0 + ty + i) * C + c0 + tx];
  __syncthreads();
#pragma unroll
  for (int i = 0; i < 32; i += 8)
    dst[(size_t)(c0 + ty + i) * R + r0 + tx] = __float2bfloat16(t[tx][ty + i]);
}

// ---------------- rope (both k and q in one launch) ----------------
__global__ void rope_kernel(const bf16* __restrict__ inK, bf16* __restrict__ outK,
                            const bf16* __restrict__ inQ, bf16* __restrict__ outQ) {
  const bf16* in = (blockIdx.y == 0) ? inK : inQ;
  bf16* out = (blockIdx.y == 0) ? outK : outQ;
  int row = blockIdx.x;       // b*2048 + s
  int d = threadIdx.x;        // 0..63
  int pos = row & 2047;
  float x1 = __bfloat162float(in[(size_t)row * 128 + d]);
  float x2 = __bfloat162float(in[(size_t)row * 128 + 64 + d]);
  float inv = exp2f(-(float)d * (13.287712379549449f / 64.0f));  // 10000^(-d/64)
  float ang = (float)pos * inv;
  float sn = sinf(ang), cs = cosf(ang);
  out[(size_t)row * 128 + d]      = __float2bfloat16(x1 * cs - x2 * sn);
  out[(size_t)row * 128 + 64 + d] = __float2bfloat16(x1 * sn + x2 * cs);
}

// ---------------- GEMM: C(MxN) = A(MxK) @ Bt(NxK)^T + bias ----------------
// m97 structure: 128x128 tile, BK=32, 4 waves (2x2), global_load_lds w=16.
template <int MODE>
__global__ __launch_bounds__(256) void gemm_bt(
    const bf16* __restrict__ A, const bf16* __restrict__ A2,
    const bf16* __restrict__ Bt,
    const float* __restrict__ b0, const float* __restrict__ b1,
    const float* __restrict__ b2,
    void* __restrict__ C0, void* __restrict__ C1,
    void* __restrict__ C2, void* __restrict__ C3,
    int M, int N, int K) {
  __shared__ bf16 sA[128 * 32];
  __shared__ bf16 sB[128 * 32];
  const int tid = threadIdx.x, lane = tid & 63, wid = tid >> 6;
  const int l15 = lane & 15, l4 = lane >> 4;
  const int m0 = blockIdx.y * 128, n0 = blockIdx.x * 128;
  const int wm = (wid >> 1) * 64, wn = (wid & 1) * 64;
  f4v acc[4][4] = {};
  const bf16* Ause = (MODE == 2 && n0 >= 4096) ? A2 : A;
  const bf16* gA = Ause + (size_t)m0 * K;
  const bf16* gB = Bt + (size_t)n0 * K;
  const int row = tid >> 2, col = (tid & 3) * 8;
  for (int k0 = 0; k0 < K; k0 += 32) {
    gld16(gA + (size_t)row * K + k0 + col,        sA + tid * 8);
    gld16(gA + (size_t)(row + 64) * K + k0 + col, sA + (tid + 256) * 8);
    gld16(gB + (size_t)row * K + k0 + col,        sB + tid * 8);
    gld16(gB + (size_t)(row + 64) * K + k0 + col, sB + (tid + 256) * 8);
    __syncthreads();
    s8v a[4], b[4];
#pragma unroll
    for (int i = 0; i < 4; i++) a[i] = *(const s8v*)(sA + (wm + i * 16 + l15) * 32 + l4 * 8);
#pragma unroll
    for (int j = 0; j < 4; j++) b[j] = *(const s8v*)(sB + (wn + j * 16 + l15) * 32 + l4 * 8);
#pragma unroll
    for (int i = 0; i < 4; i++)
#pragma unroll
      for (int j = 0; j < 4; j++) acc[i][j] = mfma16(a[i], b[j], acc[i][j]);
    __syncthreads();
  }
  // epilogue. C/D layout: row = l4*4+g, col = l15 (within 16x16 tile)
#pragma unroll
  for (int j = 0; j < 4; j++) {
    const int nb = n0 + wn + j * 16;      // 16-col tile base (uniform per j)
    const int n = nb + l15;
    if (MODE == 3) {
      const float bv = b0[n];
#pragma unroll
      for (int i = 0; i < 4; i++) {
        size_t mb = m0 + wm + i * 16 + l4 * 4;
#pragma unroll
        for (int g = 0; g < 4; g++)
          ((float*)C0)[(mb + g) * (size_t)N + n] = acc[i][j][g] + bv;
      }
    } else if (MODE == 1) {
      const float bv = b0[n];  // 1280-entry concat
      bf16* dst; int stride, nc;
      if (nb < 512)       { dst = (bf16*)C0; stride = 512; nc = n; }
      else if (nb < 1024) { dst = (bf16*)C1; stride = 512; nc = n - 512; }
      else if (nb < 1152) { dst = (bf16*)C2; stride = 128; nc = n - 1024; }
      else                { dst = (bf16*)C3; stride = 128; nc = n - 1152; }
#pragma unroll
      for (int i = 0; i < 4; i++) {
        size_t mb = m0 + wm + i * 16 + l4 * 4;
#pragma unroll
        for (int g = 0; g < 4; g++)
          dst[(mb + g) * (size_t)stride + nc] = __float2bfloat16(acc[i][j][g] + bv);
      }
    } else {  // MODE 2: UK (k_c) | UV (vT) | UQ (q_c)
      if (nb < 2048) {
        const float bv = b0[n];
        bf16* dst = (bf16*)C0;
#pragma unroll
        for (int i = 0; i < 4; i++) {
          size_t mb = m0 + wm + i * 16 + l4 * 4;
#pragma unroll
          for (int g = 0; g < 4; g++)
            dst[(mb + g) * (size_t)2048 + n] = __float2bfloat16(acc[i][j][g] + bv);
        }
      } else if (nb < 4096) {
        const float bv = b1[n - 2048];
        bf16* dst = (bf16*)C1;
        int nn = n - 2048, hh = nn >> 7, dd = nn & 127;
#pragma unroll
        for (int i = 0; i < 4; i++) {
          int m = m0 + wm + i * 16 + l4 * 4;
          int bb = m >> 11, ss = m & 2047;
          unsigned int lo = f2bfu(acc[i][j][0] + bv) | ((unsigned int)f2bfu(acc[i][j][1] + bv) << 16);
          unsigned int hi = f2bfu(acc[i][j][2] + bv) | ((unsigned int)f2bfu(acc[i][j][3] + bv) << 16);
          size_t dstoff = ((size_t)(bb * 16 + hh) * 128 + dd) * 2048 + ss;
          uint2 pk; pk.x = lo; pk.y = hi;
          *reinterpret_cast<uint2*>(dst + dstoff) = pk;
        }
      } else {
        const float bv = b2[n - 4096];
        bf16* dst = (bf16*)C2;
        int nn = n - 4096;
#pragma unroll
        for (int i = 0; i < 4; i++) {
          size_t mb = m0 + wm + i * 16 + l4 * 4;
#pragma unroll
          for (int g = 0; g < 4; g++)
            dst[(mb + g) * (size_t)2048 + nn] = __float2bfloat16(acc[i][j][g] + bv);
        }
      }
    }
  }
}

// ---------------- flash attention (32x32 MFMA, no-max softmax, swapped QK, dbuf) ----------------
// grid (S/128, B*NH), 256 thr (4 waves; wave owns 32 q-rows). BN=32 keys/iter.
// LDS: sK/sKr/sVT[2] 8KB each -> 48KB, 2 blocks/CU. One barrier/iter; prefetch
// in flight across compute. All MFMAs 32x32x16 (24/wave-iter vs 48 at 16x16):
// QK swapped (A=K, B=Q): D col=l31=q, row=key=(reg&3)+8*(reg>>2)+4*hi -> lane
// owns one q-row's 16 P vals. PV A-frag (q=l31, k=16ks+8hi+j) built with only
// a lane^32 exchange: 4 ds_bpermute + selects (was 16 bperm = the 4.19M
// conflict cycles). Two QK accs (Kc,Kr) for dep-chain ILP=2.
__global__ __launch_bounds__(256, 2) void flash_attn(
    const bf16* __restrict__ Qc, const bf16* __restrict__ Kc,
    const bf16* __restrict__ Qr, const bf16* __restrict__ Kr,
    const bf16* __restrict__ VT, const int* __restrict__ amask,
    bf16* __restrict__ ctx) {
  const int S = 2048, H = 2048, D = 128;
  __shared__ bf16 sK[2][16 * 32 * 8];
  __shared__ bf16 sKr[2][16 * 32 * 8];
  __shared__ bf16 sVT[2][4 * 128 * 8];

  const int tid = threadIdx.x, lane = tid & 63, wid = tid >> 6;
  const int l31 = lane & 31, hi = lane >> 5;
  const int qt = blockIdx.x, bh = blockIdx.y;
  const int b = bh >> 4, h = bh & 15;
  const size_t bS = (size_t)b * S;
  const int q0 = qt * 128 + wid * 32;

  // Q fragments (B-operand of swapped QK): q = q0+l31, k(d) = t*16 + hi*8 + j
  s8v qcf[8], qrf[8];
  {
    const bf16* pc = Qc + (bS + q0 + l31) * H + h * D + hi * 8;
    const bf16* pr = Qr + (bS + q0 + l31) * D + hi * 8;
#pragma unroll
    for (int t = 0; t < 8; t++) {
      qcf[t] = *(const s8v*)(pc + t * 16);
      qrf[t] = *(const s8v*)(pr + t * 16);
    }
  }

  f16v oacc[4] = {};   // [dblk]: col=l31 -> d=dblk*32+l31; row(reg)=q pattern
  float lsum = 0.f;
  const float scl = 0.08838834764831845f;  // 1/sqrt(128)

  auto stage = [&](int buf, int kv) {
#pragma unroll
    for (int p = 0; p < 2; p++) {
      int idx = tid + p * 256;
      int key = (idx & 31), dch = (idx >> 5);
      gld16(Kc + (bS + kv + key) * H + h * D + dch * 8, sK[buf] + idx * 8);
      gld16(Kr + (bS + kv + key) * D + dch * 8, sKr[buf] + idx * 8);
      int d = (idx & 127), kch = (idx >> 7);
      gld16(VT + ((size_t)bh * D + d) * S + kv + kch * 8, sVT[buf] + idx * 8);
    }
  };

  const int xaddr = (lane ^ 32) * 4;   // bpermute: partner lane (hi flip)

  stage(0, 0);
  for (int it = 0; it < 64; ++it) {
    const int cur = it & 1;
    const int kv0 = it * 32;
    __syncthreads();                       // drains cur's loads; prev reads done
    if (it + 1 < 64) stage(cur ^ 1, (it + 1) * 32);  // prefetch across compute

    // mask: lane's keys live at kv0 + 8*g2 + 4*hi + (0..3)
    int4 m4[4];
#pragma unroll
    for (int g2 = 0; g2 < 4; g2++)
      m4[g2] = *(const int4*)(amask + bS + kv0 + 8 * g2 + 4 * hi);

    // S^T = Kc.Qc^T + Kr.Qr^T (swapped, 32x32x16): A row=key=l31, k=hi*8+j ->
    // d = t*16+hi*8+j -> sK[dch=2t+hi][key=l31]. Two accs = 2 indep chains.
    f16v scc = {}, scr = {};
    __builtin_amdgcn_s_setprio(1);
#pragma unroll
    for (int t = 0; t < 8; t++) {
      s8v kf = *(const s8v*)(sK[cur] + ((2 * t + hi) * 32 + l31) * 8);
      scc = mfma32(kf, qcf[t], scc);
      s8v rf = *(const s8v*)(sKr[cur] + ((2 * t + hi) * 32 + l31) * 8);
      scr = mfma32(rf, qrf[t], scr);
    }
    __builtin_amdgcn_s_setprio(0);

    // no-max softmax over lane's 16 keys: reg r -> key (r&3)+8*(r>>2)+4*hi.
    // pk2[g2][w] packs keys 8*g2+4*hi+{2w,2w+1} (consecutive).
    unsigned int pk2[4][2];
#pragma unroll
    for (int g2 = 0; g2 < 4; g2++) {
      const int* mm = (const int*)&m4[g2];
#pragma unroll
      for (int w = 0; w < 2; w++) {
        int r = 4 * g2 + 2 * w;
        float pa = mm[2 * w]     ? __expf((scc[r] + scr[r]) * scl) : 0.f;
        float pb = mm[2 * w + 1] ? __expf((scc[r + 1] + scr[r + 1]) * scl) : 0.f;
        lsum += pa + pb;
        pk2[g2][w] = (unsigned int)f2bfu(pa) | ((unsigned int)f2bfu(pb) << 16);
      }
    }

    // PV A-frag (q=l31, k=16*ks+8*hi+j): own run g2=2ks+hi + partner's same-g2
    // half. Lane passes its g2=2ks+(hi^1) packs; receives partner's g2=2ks+hi.
    s8v pf[2];
#pragma unroll
    for (int ks = 0; ks < 2; ks++) {
      int passA = hi ? (int)pk2[2 * ks][0] : (int)pk2[2 * ks + 1][0];
      int passB = hi ? (int)pk2[2 * ks][1] : (int)pk2[2 * ks + 1][1];
      int recvA = __builtin_amdgcn_ds_bpermute(xaddr, passA);
      int recvB = __builtin_amdgcn_ds_bpermute(xaddr, passB);
      union { int w[4]; s8v v; } u;
      u.w[0] = hi ? recvA : (int)pk2[2 * ks][0];
      u.w[1] = hi ? recvB : (int)pk2[2 * ks][1];
      u.w[2] = hi ? (int)pk2[2 * ks + 1][0] : recvA;
      u.w[3] = hi ? (int)pk2[2 * ks + 1][1] : recvB;
      pf[ks] = u.v;
    }

    // O += P @ V (32x32x16): B col=l31=d, k=hi*8+j -> key=16ks+8hi+j ->
    // sVT[kch=2ks+hi][d]. 4 indep acc chains (dblk), depth 2.
    __builtin_amdgcn_s_setprio(1);
#pragma unroll
    for (int dblk = 0; dblk < 4; dblk++) {
      s8v vf0 = *(const s8v*)(sVT[cur] + ((0 + hi) * 128 + dblk * 32 + l31) * 8);
      oacc[dblk] = mfma32(pf[0], vf0, oacc[dblk]);
      s8v vf1 = *(const s8v*)(sVT[cur] + ((2 + hi) * 128 + dblk * 32 + l31) * 8);
      oacc[dblk] = mfma32(pf[1], vf1, oacc[dblk]);
    }
    __builtin_amdgcn_s_setprio(0);
  }

  // row sums: lane's lsum covers 16 of 32 keys/iter for q=l31; partner (^32)
  // has the rest -> one xor reduce gives the full sum per q=l31.
  float s = lsum;
  s += __shfl_xor(s, 32, 64);
  float inv[16];
#pragma unroll
  for (int g = 0; g < 16; g++) {
    int ql = (g & 3) + 8 * (g >> 2) + 4 * hi;   // oacc reg g's q (0..31)
    inv[g] = 1.0f / __shfl(s, ql, 64);
  }

  // normalize + store ctx (B,S,H): oacc[dblk][g] -> q=pattern, d=dblk*32+l31
#pragma unroll
  for (int dblk = 0; dblk < 4; dblk++)
#pragma unroll
    for (int g = 0; g < 16; g++) {
      int qrow = q0 + (g & 3) + 8 * (g >> 2) + 4 * hi;
      ctx[(bS + qrow) * H + h * D + dblk * 32 + l31] =
          __float2bfloat16(oacc[dblk][g] * inv[g]);
    }
}

// ---------------- launch ----------------
extern "C" void kernel_launch(void* const* d_in, const int* in_sizes, int n_in,
                              void* d_out, int out_size, void* d_ws, size_t ws_size,
                              hipStream_t stream) {
  const float* hs    = (const float*)d_in[0];
  const int*   amask = (const int*)d_in[1];
  const float* W_DKV = (const float*)d_in[2];  const float* b_DKV = (const float*)d_in[3];
  const float* W_DQ  = (const float*)d_in[4];  const float* b_DQ  = (const float*)d_in[5];
  const float* W_UK  = (const float*)d_in[6];  const float* b_UK  = (const float*)d_in[7];
  const float* W_UV  = (const float*)d_in[8];  const float* b_UV  = (const float*)d_in[9];
  const float* W_UQ  = (const float*)d_in[10]; const float* b_UQ  = (const float*)d_in[11];
  const float* W_KR  = (const float*)d_in[12]; const float* b_KR  = (const float*)d_in[13];
  const float* W_QR  = (const float*)d_in[14]; const float* b_QR  = (const float*)d_in[15];
  const float* W_O   = (const float*)d_in[16]; const float* b_O   = (const float*)d_in[17];

  char* wsb = (char*)d_ws;
  size_t off = 0;
  auto allocB = [&](size_t bytes) {
    void* p = wsb + off; off = (off + bytes + 255) & ~(size_t)255; return p;
  };
  float* bcat  = (float*)allocB(1280 * 4);
  bf16* hsb    = (bf16*)allocB((size_t)4096 * 2048 * 2);
  bf16* wt_dkv = (bf16*)allocB((size_t)512 * 2048 * 2);
  bf16* wt_dq  = (bf16*)allocB((size_t)512 * 2048 * 2);
  bf16* wt_kr  = (bf16*)allocB((size_t)128 * 2048 * 2);
  bf16* wt_qr  = (bf16*)allocB((size_t)128 * 2048 * 2);
  // wt_uk|wt_uv|wt_uq MUST stay contiguous (single Bt for the merged GEMM):
  bf16* wt_uk  = (bf16*)allocB((size_t)2048 * 512 * 2);
  bf16* wt_uv  = (bf16*)allocB((size_t)2048 * 512 * 2);
  bf16* wt_uq  = (bf16*)allocB((size_t)2048 * 512 * 2);
  bf16* wt_o   = (bf16*)allocB((size_t)2048 * 2048 * 2);
  bf16* c_kv   = (bf16*)allocB((size_t)4096 * 512 * 2);
  bf16* c_q    = (bf16*)allocB((size_t)4096 * 512 * 2);
  bf16* krl    = (bf16*)allocB((size_t)4096 * 128 * 2);
  bf16* qrl    = (bf16*)allocB((size_t)4096 * 128 * 2);
  bf16* k_r    = (bf16*)allocB((size_t)4096 * 128 * 2);
  bf16* q_r    = (bf16*)allocB((size_t)4096 * 128 * 2);
  bf16* k_c    = (bf16*)allocB((size_t)4096 * 2048 * 2);
  bf16* q_c    = (bf16*)allocB((size_t)4096 * 2048 * 2);
  bf16* vT     = (bf16*)allocB((size_t)4096 * 2048 * 2);
  bf16* ctx    = (bf16*)allocB((size_t)4096 * 2048 * 2);
  (void)wt_uv; (void)wt_uq;

  // one-shot ingest: 4096 hs-convert + 1 bias-concat + 9728 transpose tiles
  prep<<<13825, 256, 0, stream>>>(hs, hsb,
      b_DKV, b_DQ, b_KR, b_QR, bcat,
      W_DKV, wt_dkv, W_DQ, wt_dq, W_KR, wt_kr, W_QR, wt_qr,
      W_UK, wt_uk, W_UV, wt_uv, W_UQ, wt_uq, W_O, wt_o);

  // fused projections: N = 512|512|128|128 = 1280, K = 2048
  gemm_bt<1><<<dim3(10, 32), 256, 0, stream>>>(
      hsb, nullptr, wt_dkv, bcat, nullptr, nullptr,
      c_kv, c_q, krl, qrl, 4096, 1280, 2048);
  rope_kernel<<<dim3(4096, 2), 64, 0, stream>>>(krl, k_r, qrl, q_r);

  // merged UK|UV|UQ: N = 2048*3 = 6144, K = 512 (A = c_kv for n<4096, c_q above)
  gemm_bt<2><<<dim3(48, 32), 256, 0, stream>>>(
      c_kv, c_q, wt_uk, b_UK, b_UV, b_UQ,
      k_c, vT, q_c, nullptr, 4096, 6144, 512);

  // attention: grid (2048/128, 32) = 512 blocks, 2 blocks/CU (48KB LDS)
  flash_attn<<<dim3(16, 32), 256, 0, stream>>>(q_c, k_c, q_r, k_r, vT, amask, ctx);

  // output projection (fp32 out)
  gemm_bt<3><<<dim3(16, 32), 256, 0, stream>>>(
      ctx, nullptr, wt_o, b_O, nullptr, nullptr,
      d_out, nullptr, nullptr, nullptr, 4096, 2048, 2048);
}

// Round 7
// 450.554 us; speedup vs baseline: 1.1218x; 1.0338x over previous
//
#include <hip/hip_runtime.h>
#include <hip/hip_bf16.h>
#include <stdint.h>

// MLA forward: B=2,S=2048,H=2048,NH=16,D=128,LAT=512. Inputs fp32 (R3-proven).
// R16: flash = R15 (32x32 MFMA, swapped QK, 0 bank conflicts) + T3/T4 counted
// vmcnt pipeline. R15 proved the kernel is BARRIER-DRAIN bound: __syncthreads
// emits s_waitcnt vmcnt(0) -> the prefetch never survives the barrier; every
// iter eats full staging latency (MfmaUtil 24% with all pipes <30%). Fix:
// triple-buffer LDS (72KB, still 2 blk/CU) + raw s_barrier + explicit
// s_waitcnt vmcnt(10) (waits ONLY tile t's 6 loads; t+1's 6 + 4 mask loads
// stay in flight) + sched_barrier(0) fence (guide rule #18). Masks double-
// buffered in regs so their compiler waits don't drain staging (vmcnt FIFO).
typedef __hip_bfloat16 bf16;
typedef __attribute__((ext_vector_type(8))) short s8v;    // 8 x bf16 (4 VGPRs)
typedef __attribute__((ext_vector_type(4))) float f4v;    // 16x16 accum
typedef __attribute__((ext_vector_type(16))) float f16v;  // 32x32 accum

__device__ __forceinline__ void gld16(const bf16* g, bf16* l) {
  __builtin_amdgcn_global_load_lds(
      (__attribute__((address_space(1))) unsigned int*)g,
      (__attribute__((address_space(3))) unsigned int*)l, 16, 0, 0);
}

__device__ __forceinline__ f4v mfma16(s8v a, s8v b, f4v c) {
  return __builtin_amdgcn_mfma_f32_16x16x32_bf16(a, b, c, 0, 0, 0);
}

__device__ __forceinline__ f16v mfma32(s8v a, s8v b, f16v c) {
  return __builtin_amdgcn_mfma_f32_32x32x16_bf16(a, b, c, 0, 0, 0);
}

__device__ __forceinline__ unsigned short f2bfu(float f) {
  union { bf16 h; unsigned short u; } cv;
  cv.h = __float2bfloat16(f);
  return cv.u;
}

// ---------------- prep: hs fp32->bf16 + 8 weight transposes + bias concat ----------------
__global__ __launch_bounds__(256) void prep(
    const float* __restrict__ hs, bf16* __restrict__ hsb,
    const float* __restrict__ bdkv, const float* __restrict__ bdq,
    const float* __restrict__ bkr, const float* __restrict__ bqr,
    float* __restrict__ bcat,
    const float* __restrict__ wdkv, bf16* __restrict__ tdkv,
    const float* __restrict__ wdq,  bf16* __restrict__ tdq,
    const float* __restrict__ wkr,  bf16* __restrict__ tkr,
    const float* __restrict__ wqr,  bf16* __restrict__ tqr,
    const float* __restrict__ wuk,  bf16* __restrict__ tuk,
    const float* __restrict__ wuv,  bf16* __restrict__ tuv,
    const float* __restrict__ wuq,  bf16* __restrict__ tuq,
    const float* __restrict__ wo,   bf16* __restrict__ to_) {
  int bid = blockIdx.x;
  int tid = threadIdx.x;
  if (bid < 4096) {
    int i = (bid * 256 + tid) * 8;
    union { s8v v; unsigned short u[8]; } pk;
#pragma unroll
    for (int j = 0; j < 8; j++) pk.u[j] = f2bfu(hs[i + j]);
    *(s8v*)(hsb + i) = pk.v;
    return;
  }
  if (bid == 4096) {
#pragma unroll
    for (int p = 0; p < 5; p++) {
      int i = tid + p * 256;
      float v;
      if (i < 512)       v = bdkv[i];
      else if (i < 1024) v = bdq[i - 512];
      else if (i < 1152) v = bkr[i - 1024];
      else               v = bqr[i - 1152];
      bcat[i] = v;
    }
    return;
  }
  bid -= 4097;
  const float* src; bf16* dst; int R, C;
  if      (bid < 1024) { src = wdkv; dst = tdkv; R = 2048; C = 512;  }
  else if (bid < 2048) { src = wdq;  dst = tdq;  R = 2048; C = 512;  bid -= 1024; }
  else if (bid < 2304) { src = wkr;  dst = tkr;  R = 2048; C = 128;  bid -= 2048; }
  else if (bid < 2560) { src = wqr;  dst = tqr;  R = 2048; C = 128;  bid -= 2304; }
  else if (bid < 3584) { src = wuk;  dst = tuk;  R = 512;  C = 2048; bid -= 2560; }
  else if (bid < 4608) { src = wuv;  dst = tuv;  R = 512;  C = 2048; bid -= 3584; }
  else if (bid < 5632) { src = wuq;  dst = tuq;  R = 512;  C = 2048; bid -= 4608; }
  else                 { src = wo;   dst = to_;  R = 2048; C = 2048; bid -= 5632; }
  __shared__ float t[32][33];
  int C32 = C >> 5;
  int bx = bid % C32, by = bid / C32;
  int tx = tid & 31, ty = tid >> 5;
  int c0 = bx * 32, r0 = by * 32;
#pragma unroll
  for (int i = 0; i < 32; i += 8)
    t[ty + i][tx] = src[(size_t)(r0 + ty + i) * C + c0 + tx];
  __syncthreads();
#pragma unroll
  for (int i = 0; i < 32; i += 8)
    dst[(size_t)(c0 + ty + i) * R + r0 + tx] = __float2bfloat16(t[tx][ty + i]);
}

// ---------------- rope (both k and q in one launch) ----------------
__global__ void rope_kernel(const bf16* __restrict__ inK, bf16* __restrict__ outK,
                            const bf16* __restrict__ inQ, bf16* __restrict__ outQ) {
  const bf16* in = (blockIdx.y == 0) ? inK : inQ;
  bf16* out = (blockIdx.y == 0) ? outK : outQ;
  int row = blockIdx.x;       // b*2048 + s
  int d = threadIdx.x;        // 0..63
  int pos = row & 2047;
  float x1 = __bfloat162float(in[(size_t)row * 128 + d]);
  float x2 = __bfloat162float(in[(size_t)row * 128 + 64 + d]);
  float inv = exp2f(-(float)d * (13.287712379549449f / 64.0f));  // 10000^(-d/64)
  float ang = (float)pos * inv;
  float sn = sinf(ang), cs = cosf(ang);
  out[(size_t)row * 128 + d]      = __float2bfloat16(x1 * cs - x2 * sn);
  out[(size_t)row * 128 + 64 + d] = __float2bfloat16(x1 * sn + x2 * cs);
}

// ---------------- GEMM: C(MxN) = A(MxK) @ Bt(NxK)^T + bias ----------------
// m97 structure: 128x128 tile, BK=32, 4 waves (2x2), global_load_lds w=16.
template <int MODE>
__global__ __launch_bounds__(256) void gemm_bt(
    const bf16* __restrict__ A, const bf16* __restrict__ A2,
    const bf16* __restrict__ Bt,
    const float* __restrict__ b0, const float* __restrict__ b1,
    const float* __restrict__ b2,
    void* __restrict__ C0, void* __restrict__ C1,
    void* __restrict__ C2, void* __restrict__ C3,
    int M, int N, int K) {
  __shared__ bf16 sA[128 * 32];
  __shared__ bf16 sB[128 * 32];
  const int tid = threadIdx.x, lane = tid & 63, wid = tid >> 6;
  const int l15 = lane & 15, l4 = lane >> 4;
  const int m0 = blockIdx.y * 128, n0 = blockIdx.x * 128;
  const int wm = (wid >> 1) * 64, wn = (wid & 1) * 64;
  f4v acc[4][4] = {};
  const bf16* Ause = (MODE == 2 && n0 >= 4096) ? A2 : A;
  const bf16* gA = Ause + (size_t)m0 * K;
  const bf16* gB = Bt + (size_t)n0 * K;
  const int row = tid >> 2, col = (tid & 3) * 8;
  for (int k0 = 0; k0 < K; k0 += 32) {
    gld16(gA + (size_t)row * K + k0 + col,        sA + tid * 8);
    gld16(gA + (size_t)(row + 64) * K + k0 + col, sA + (tid + 256) * 8);
    gld16(gB + (size_t)row * K + k0 + col,        sB + tid * 8);
    gld16(gB + (size_t)(row + 64) * K + k0 + col, sB + (tid + 256) * 8);
    __syncthreads();
    s8v a[4], b[4];
#pragma unroll
    for (int i = 0; i < 4; i++) a[i] = *(const s8v*)(sA + (wm + i * 16 + l15) * 32 + l4 * 8);
#pragma unroll
    for (int j = 0; j < 4; j++) b[j] = *(const s8v*)(sB + (wn + j * 16 + l15) * 32 + l4 * 8);
#pragma unroll
    for (int i = 0; i < 4; i++)
#pragma unroll
      for (int j = 0; j < 4; j++) acc[i][j] = mfma16(a[i], b[j], acc[i][j]);
    __syncthreads();
  }
  // epilogue. C/D layout: row = l4*4+g, col = l15 (within 16x16 tile)
#pragma unroll
  for (int j = 0; j < 4; j++) {
    const int nb = n0 + wn + j * 16;      // 16-col tile base (uniform per j)
    const int n = nb + l15;
    if (MODE == 3) {
      const float bv = b0[n];
#pragma unroll
      for (int i = 0; i < 4; i++) {
        size_t mb = m0 + wm + i * 16 + l4 * 4;
#pragma unroll
        for (int g = 0; g < 4; g++)
          ((float*)C0)[(mb + g) * (size_t)N + n] = acc[i][j][g] + bv;
      }
    } else if (MODE == 1) {
      const float bv = b0[n];  // 1280-entry concat
      bf16* dst; int stride, nc;
      if (nb < 512)       { dst = (bf16*)C0; stride = 512; nc = n; }
      else if (nb < 1024) { dst = (bf16*)C1; stride = 512; nc = n - 512; }
      else if (nb < 1152) { dst = (bf16*)C2; stride = 128; nc = n - 1024; }
      else                { dst = (bf16*)C3; stride = 128; nc = n - 1152; }
#pragma unroll
      for (int i = 0; i < 4; i++) {
        size_t mb = m0 + wm + i * 16 + l4 * 4;
#pragma unroll
        for (int g = 0; g < 4; g++)
          dst[(mb + g) * (size_t)stride + nc] = __float2bfloat16(acc[i][j][g] + bv);
      }
    } else {  // MODE 2: UK (k_c) | UV (vT) | UQ (q_c)
      if (nb < 2048) {
        const float bv = b0[n];
        bf16* dst = (bf16*)C0;
#pragma unroll
        for (int i = 0; i < 4; i++) {
          size_t mb = m0 + wm + i * 16 + l4 * 4;
#pragma unroll
          for (int g = 0; g < 4; g++)
            dst[(mb + g) * (size_t)2048 + n] = __float2bfloat16(acc[i][j][g] + bv);
        }
      } else if (nb < 4096) {
        const float bv = b1[n - 2048];
        bf16* dst = (bf16*)C1;
        int nn = n - 2048, hh = nn >> 7, dd = nn & 127;
#pragma unroll
        for (int i = 0; i < 4; i++) {
          int m = m0 + wm + i * 16 + l4 * 4;
          int bb = m >> 11, ss = m & 2047;
          unsigned int lo = f2bfu(acc[i][j][0] + bv) | ((unsigned int)f2bfu(acc[i][j][1] + bv) << 16);
          unsigned int hi = f2bfu(acc[i][j][2] + bv) | ((unsigned int)f2bfu(acc[i][j][3] + bv) << 16);
          size_t dstoff = ((size_t)(bb * 16 + hh) * 128 + dd) * 2048 + ss;
          uint2 pk; pk.x = lo; pk.y = hi;
          *reinterpret_cast<uint2*>(dst + dstoff) = pk;
        }
      } else {
        const float bv = b2[n - 4096];
        bf16* dst = (bf16*)C2;
        int nn = n - 4096;
#pragma unroll
        for (int i = 0; i < 4; i++) {
          size_t mb = m0 + wm + i * 16 + l4 * 4;
#pragma unroll
          for (int g = 0; g < 4; g++)
            dst[(mb + g) * (size_t)2048 + nn] = __float2bfloat16(acc[i][j][g] + bv);
        }
      }
    }
  }
}

// ---------------- flash attention (32x32 MFMA, counted-vmcnt pipeline) ----------------
// grid (S/128, B*NH), 256 thr (4 waves; wave owns 32 q-rows). BN=32 keys/iter.
// LDS: TRIPLE-buffered sK/sKr/sVT (8KB each) -> 72KB, 2 blocks/CU. Sync per
// iter: s_waitcnt vmcnt(10) [tile t's 6 loads done; t+1's 6 + mask 4 in
// flight] -> raw s_barrier -> sched_barrier(0). Stage(t+2) + mask(t+1) issued
// after -> ~2 compute phases of latency cover, never drained. Buffer t+2
// overwrites buf[(t-1)%3], safe: all waves' t-1 reads completed pre-barrier
// (compiler lgkm waits before MFMA use). vmcnt FIFO: stage(t) always oldest.
__global__ __launch_bounds__(256, 2) void flash_attn(
    const bf16* __restrict__ Qc, const bf16* __restrict__ Kc,
    const bf16* __restrict__ Qr, const bf16* __restrict__ Kr,
    const bf16* __restrict__ VT, const int* __restrict__ amask,
    bf16* __restrict__ ctx) {
  const int S = 2048, H = 2048, D = 128;
  __shared__ bf16 sK[3][16 * 32 * 8];
  __shared__ bf16 sKr[3][16 * 32 * 8];
  __shared__ bf16 sVT[3][4 * 128 * 8];

  const int tid = threadIdx.x, lane = tid & 63, wid = tid >> 6;
  const int l31 = lane & 31, hi = lane >> 5;
  const int qt = blockIdx.x, bh = blockIdx.y;
  const int b = bh >> 4, h = bh & 15;
  const size_t bS = (size_t)b * S;
  const int q0 = qt * 128 + wid * 32;

  // Q fragments (B-operand of swapped QK): q = q0+l31, k(d) = t*16 + hi*8 + j
  s8v qcf[8], qrf[8];
  {
    const bf16* pc = Qc + (bS + q0 + l31) * H + h * D + hi * 8;
    const bf16* pr = Qr + (bS + q0 + l31) * D + hi * 8;
#pragma unroll
    for (int t = 0; t < 8; t++) {
      qcf[t] = *(const s8v*)(pc + t * 16);
      qrf[t] = *(const s8v*)(pr + t * 16);
    }
  }

  f16v oacc[4] = {};   // [dblk]: col=l31 -> d=dblk*32+l31; row(reg)=q pattern
  float lsum = 0.f;
  const float scl = 0.08838834764831845f;  // 1/sqrt(128)

  auto stage = [&](int buf, int kv) {
#pragma unroll
    for (int p = 0; p < 2; p++) {
      int idx = tid + p * 256;
      int key = (idx & 31), dch = (idx >> 5);
      gld16(Kc + (bS + kv + key) * H + h * D + dch * 8, sK[buf] + idx * 8);
      gld16(Kr + (bS + kv + key) * D + dch * 8, sKr[buf] + idx * 8);
      int d = (idx & 127), kch = (idx >> 7);
      gld16(VT + ((size_t)bh * D + d) * S + kv + kch * 8, sVT[buf] + idx * 8);
    }
  };

  const int xaddr = (lane ^ 32) * 4;   // bpermute: partner lane (hi flip)

  // prologue: stage tiles 0,1 + masks for tile 0 (queue: st0[6] mv0[4] st1[6])
  int4 mvC[4], mvN[4];
  stage(0, 0);
#pragma unroll
  for (int g2 = 0; g2 < 4; g2++)
    mvC[g2] = *(const int4*)(amask + bS + 8 * g2 + 4 * hi);
  stage(1, 32);

  for (int it = 0; it < 64; ++it) {
    const int cur = it % 3;
    const int kv0 = it * 32;
    // wait for tile `it` only: outstanding <= st(it)[6]+mv(it)[4]+st(it+1)[6];
    // vmcnt(10) retires the oldest 6 = st(it). Last iter: full drain (cheap,
    // reorder-proof).
    if (it < 63) asm volatile("s_waitcnt vmcnt(10)" ::: "memory");
    else         asm volatile("s_waitcnt vmcnt(0)" ::: "memory");
    __builtin_amdgcn_s_barrier();
    __builtin_amdgcn_sched_barrier(0);   // no ds_read hoisted above the sync

    // prefetch mask(t+1) then stage(t+2) (order keeps st(t+1) older than both)
    if (it + 1 < 64) {
#pragma unroll
      for (int g2 = 0; g2 < 4; g2++)
        mvN[g2] = *(const int4*)(amask + bS + kv0 + 32 + 8 * g2 + 4 * hi);
    } else {
#pragma unroll
      for (int g2 = 0; g2 < 4; g2++) mvN[g2] = mvC[g2];
    }
    if (it + 2 < 64) stage((it + 2) % 3, kv0 + 64);

    // S^T = Kc.Qc^T + Kr.Qr^T (swapped, 32x32x16): A row=key=l31, k=hi*8+j ->
    // d = t*16+hi*8+j -> sK[dch=2t+hi][key=l31]. Two accs = 2 indep chains.
    f16v scc = {}, scr = {};
    __builtin_amdgcn_s_setprio(1);
#pragma unroll
    for (int t = 0; t < 8; t++) {
      s8v kf = *(const s8v*)(sK[cur] + ((2 * t + hi) * 32 + l31) * 8);
      scc = mfma32(kf, qcf[t], scc);
      s8v rf = *(const s8v*)(sKr[cur] + ((2 * t + hi) * 32 + l31) * 8);
      scr = mfma32(rf, qrf[t], scr);
    }
    __builtin_amdgcn_s_setprio(0);

    // no-max softmax over lane's 16 keys: reg r -> key (r&3)+8*(r>>2)+4*hi.
    // pk2[g2][w] packs keys 8*g2+4*hi+{2w,2w+1} (consecutive).
    unsigned int pk2[4][2];
#pragma unroll
    for (int g2 = 0; g2 < 4; g2++) {
      const int* mm = (const int*)&mvC[g2];
#pragma unroll
      for (int w = 0; w < 2; w++) {
        int r = 4 * g2 + 2 * w;
        float pa = mm[2 * w]     ? __expf((scc[r] + scr[r]) * scl) : 0.f;
        float pb = mm[2 * w + 1] ? __expf((scc[r + 1] + scr[r + 1]) * scl) : 0.f;
        lsum += pa + pb;
        pk2[g2][w] = (unsigned int)f2bfu(pa) | ((unsigned int)f2bfu(pb) << 16);
      }
    }

    // PV A-frag (q=l31, k=16*ks+8*hi+j): own run g2=2ks+hi + partner's same-g2
    // half. Lane passes its g2=2ks+(hi^1) packs; receives partner's g2=2ks+hi.
    s8v pf[2];
#pragma unroll
    for (int ks = 0; ks < 2; ks++) {
      int passA = hi ? (int)pk2[2 * ks][0] : (int)pk2[2 * ks + 1][0];
      int passB = hi ? (int)pk2[2 * ks][1] : (int)pk2[2 * ks + 1][1];
      int recvA = __builtin_amdgcn_ds_bpermute(xaddr, passA);
      int recvB = __builtin_amdgcn_ds_bpermute(xaddr, passB);
      union { int w[4]; s8v v; } u;
      u.w[0] = hi ? recvA : (int)pk2[2 * ks][0];
      u.w[1] = hi ? recvB : (int)pk2[2 * ks][1];
      u.w[2] = hi ? (int)pk2[2 * ks + 1][0] : recvA;
      u.w[3] = hi ? (int)pk2[2 * ks + 1][1] : recvB;
      pf[ks] = u.v;
    }

    // O += P @ V (32x32x16): B col=l31=d, k=hi*8+j -> key=16ks+8hi+j ->
    // sVT[kch=2ks+hi][d]. 4 indep acc chains (dblk), depth 2.
    __builtin_amdgcn_s_setprio(1);
#pragma unroll
    for (int dblk = 0; dblk < 4; dblk++) {
      s8v vf0 = *(const s8v*)(sVT[cur] + ((0 + hi) * 128 + dblk * 32 + l31) * 8);
      oacc[dblk] = mfma32(pf[0], vf0, oacc[dblk]);
      s8v vf1 = *(const s8v*)(sVT[cur] + ((2 + hi) * 128 + dblk * 32 + l31) * 8);
      oacc[dblk] = mfma32(pf[1], vf1, oacc[dblk]);
    }
    __builtin_amdgcn_s_setprio(0);

#pragma unroll
    for (int g2 = 0; g2 < 4; g2++) mvC[g2] = mvN[g2];
  }

  // row sums: lane's lsum covers 16 of 32 keys/iter for q=l31; partner (^32)
  // has the rest -> one xor reduce gives the full sum per q=l31.
  float s = lsum;
  s += __shfl_xor(s, 32, 64);
  float inv[16];
#pragma unroll
  for (int g = 0; g < 16; g++) {
    int ql = (g & 3) + 8 * (g >> 2) + 4 * hi;   // oacc reg g's q (0..31)
    inv[g] = 1.0f / __shfl(s, ql, 64);
  }

  // normalize + store ctx (B,S,H): oacc[dblk][g] -> q=pattern, d=dblk*32+l31
#pragma unroll
  for (int dblk = 0; dblk < 4; dblk++)
#pragma unroll
    for (int g = 0; g < 16; g++) {
      int qrow = q0 + (g & 3) + 8 * (g >> 2) + 4 * hi;
      ctx[(bS + qrow) * H + h * D + dblk * 32 + l31] =
          __float2bfloat16(oacc[dblk][g] * inv[g]);
    }
}

// ---------------- launch ----------------
extern "C" void kernel_launch(void* const* d_in, const int* in_sizes, int n_in,
                              void* d_out, int out_size, void* d_ws, size_t ws_size,
                              hipStream_t stream) {
  const float* hs    = (const float*)d_in[0];
  const int*   amask = (const int*)d_in[1];
  const float* W_DKV = (const float*)d_in[2];  const float* b_DKV = (const float*)d_in[3];
  const float* W_DQ  = (const float*)d_in[4];  const float* b_DQ  = (const float*)d_in[5];
  const float* W_UK  = (const float*)d_in[6];  const float* b_UK  = (const float*)d_in[7];
  const float* W_UV  = (const float*)d_in[8];  const float* b_UV  = (const float*)d_in[9];
  const float* W_UQ  = (const float*)d_in[10]; const float* b_UQ  = (const float*)d_in[11];
  const float* W_KR  = (const float*)d_in[12]; const float* b_KR  = (const float*)d_in[13];
  const float* W_QR  = (const float*)d_in[14]; const float* b_QR  = (const float*)d_in[15];
  const float* W_O   = (const float*)d_in[16]; const float* b_O   = (const float*)d_in[17];

  char* wsb = (char*)d_ws;
  size_t off = 0;
  auto allocB = [&](size_t bytes) {
    void* p = wsb + off; off = (off + bytes + 255) & ~(size_t)255; return p;
  };
  float* bcat  = (float*)allocB(1280 * 4);
  bf16* hsb    = (bf16*)allocB((size_t)4096 * 2048 * 2);
  bf16* wt_dkv = (bf16*)allocB((size_t)512 * 2048 * 2);
  bf16* wt_dq  = (bf16*)allocB((size_t)512 * 2048 * 2);
  bf16* wt_kr  = (bf16*)allocB((size_t)128 * 2048 * 2);
  bf16* wt_qr  = (bf16*)allocB((size_t)128 * 2048 * 2);
  // wt_uk|wt_uv|wt_uq MUST stay contiguous (single Bt for the merged GEMM):
  bf16* wt_uk  = (bf16*)allocB((size_t)2048 * 512 * 2);
  bf16* wt_uv  = (bf16*)allocB((size_t)2048 * 512 * 2);
  bf16* wt_uq  = (bf16*)allocB((size_t)2048 * 512 * 2);
  bf16* wt_o   = (bf16*)allocB((size_t)2048 * 2048 * 2);
  bf16* c_kv   = (bf16*)allocB((size_t)4096 * 512 * 2);
  bf16* c_q    = (bf16*)allocB((size_t)4096 * 512 * 2);
  bf16* krl    = (bf16*)allocB((size_t)4096 * 128 * 2);
  bf16* qrl    = (bf16*)allocB((size_t)4096 * 128 * 2);
  bf16* k_r    = (bf16*)allocB((size_t)4096 * 128 * 2);
  bf16* q_r    = (bf16*)allocB((size_t)4096 * 128 * 2);
  bf16* k_c    = (bf16*)allocB((size_t)4096 * 2048 * 2);
  bf16* q_c    = (bf16*)allocB((size_t)4096 * 2048 * 2);
  bf16* vT     = (bf16*)allocB((size_t)4096 * 2048 * 2);
  bf16* ctx    = (bf16*)allocB((size_t)4096 * 2048 * 2);
  (void)wt_uv; (void)wt_uq;

  // one-shot ingest: 4096 hs-convert + 1 bias-concat + 9728 transpose tiles
  prep<<<13825, 256, 0, stream>>>(hs, hsb,
      b_DKV, b_DQ, b_KR, b_QR, bcat,
      W_DKV, wt_dkv, W_DQ, wt_dq, W_KR, wt_kr, W_QR, wt_qr,
      W_UK, wt_uk, W_UV, wt_uv, W_UQ, wt_uq, W_O, wt_o);

  // fused projections: N = 512|512|128|128 = 1280, K = 2048
  gemm_bt<1><<<dim3(10, 32), 256, 0, stream>>>(
      hsb, nullptr, wt_dkv, bcat, nullptr, nullptr,
      c_kv, c_q, krl, qrl, 4096, 1280, 2048);
  rope_kernel<<<dim3(4096, 2), 64, 0, stream>>>(krl, k_r, qrl, q_r);

  // merged UK|UV|UQ: N = 2048*3 = 6144, K = 512 (A = c_kv for n<4096, c_q above)
  gemm_bt<2><<<dim3(48, 32), 256, 0, stream>>>(
      c_kv, c_q, wt_uk, b_UK, b_UV, b_UQ,
      k_c, vT, q_c, nullptr, 4096, 6144, 512);

  // attention: grid (2048/128, 32) = 512 blocks, 2 blocks/CU (72KB LDS)
  flash_attn<<<dim3(16, 32), 256, 0, stream>>>(q_c, k_c, q_r, k_r, vT, amask, ctx);

  // output projection (fp32 out)
  gemm_bt<3><<<dim3(16, 32), 256, 0, stream>>>(
      ctx, nullptr, wt_o, b_O, nullptr, nullptr,
      d_out, nullptr, nullptr, nullptr, 4096, 2048, 2048);
}

// Round 8
// 442.877 us; speedup vs baseline: 1.1412x; 1.0173x over previous
//
#include <hip/hip_runtime.h>
#include <hip/hip_bf16.h>
#include <stdint.h>

// MLA forward: B=2,S=2048,H=2048,NH=16,D=128,LAT=512. Inputs fp32 (R3-proven).
// R17: two targeted memory-system fixes (flash compute = R16, frozen):
// (1) gemm2 MODE2 vT epilogue: was 8B stores at 4KB stride (16 lines/instr,
//     ~10x write amplification). Now per-wave LDS transpose (64x64 quadrant,
//     ds_write_b64 packed -> ds_read_b128 -> 128B-contiguous global stores).
// (2) flash XCD swizzle: default round-robin spread each head's 16 q-blocks
//     over all 8 XCDs (FETCH 144MB vs 66MB unique). Chunked remap
//     lid=(phys&7)*64+phys/8 gives each XCD 4 whole heads -> L2-local K/V.
typedef __hip_bfloat16 bf16;
typedef __attribute__((ext_vector_type(8))) short s8v;    // 8 x bf16 (4 VGPRs)
typedef __attribute__((ext_vector_type(4))) float f4v;    // 16x16 accum
typedef __attribute__((ext_vector_type(16))) float f16v;  // 32x32 accum

__device__ __forceinline__ void gld16(const bf16* g, bf16* l) {
  __builtin_amdgcn_global_load_lds(
      (__attribute__((address_space(1))) unsigned int*)g,
      (__attribute__((address_space(3))) unsigned int*)l, 16, 0, 0);
}

__device__ __forceinline__ f4v mfma16(s8v a, s8v b, f4v c) {
  return __builtin_amdgcn_mfma_f32_16x16x32_bf16(a, b, c, 0, 0, 0);
}

__device__ __forceinline__ f16v mfma32(s8v a, s8v b, f16v c) {
  return __builtin_amdgcn_mfma_f32_32x32x16_bf16(a, b, c, 0, 0, 0);
}

__device__ __forceinline__ unsigned short f2bfu(float f) {
  union { bf16 h; unsigned short u; } cv;
  cv.h = __float2bfloat16(f);
  return cv.u;
}

// ---------------- prep: hs fp32->bf16 + 8 weight transposes + bias concat ----------------
__global__ __launch_bounds__(256) void prep(
    const float* __restrict__ hs, bf16* __restrict__ hsb,
    const float* __restrict__ bdkv, const float* __restrict__ bdq,
    const float* __restrict__ bkr, const float* __restrict__ bqr,
    float* __restrict__ bcat,
    const float* __restrict__ wdkv, bf16* __restrict__ tdkv,
    const float* __restrict__ wdq,  bf16* __restrict__ tdq,
    const float* __restrict__ wkr,  bf16* __restrict__ tkr,
    const float* __restrict__ wqr,  bf16* __restrict__ tqr,
    const float* __restrict__ wuk,  bf16* __restrict__ tuk,
    const float* __restrict__ wuv,  bf16* __restrict__ tuv,
    const float* __restrict__ wuq,  bf16* __restrict__ tuq,
    const float* __restrict__ wo,   bf16* __restrict__ to_) {
  int bid = blockIdx.x;
  int tid = threadIdx.x;
  if (bid < 4096) {
    int i = (bid * 256 + tid) * 8;
    union { s8v v; unsigned short u[8]; } pk;
#pragma unroll
    for (int j = 0; j < 8; j++) pk.u[j] = f2bfu(hs[i + j]);
    *(s8v*)(hsb + i) = pk.v;
    return;
  }
  if (bid == 4096) {
#pragma unroll
    for (int p = 0; p < 5; p++) {
      int i = tid + p * 256;
      float v;
      if (i < 512)       v = bdkv[i];
      else if (i < 1024) v = bdq[i - 512];
      else if (i < 1152) v = bkr[i - 1024];
      else               v = bqr[i - 1152];
      bcat[i] = v;
    }
    return;
  }
  bid -= 4097;
  const float* src; bf16* dst; int R, C;
  if      (bid < 1024) { src = wdkv; dst = tdkv; R = 2048; C = 512;  }
  else if (bid < 2048) { src = wdq;  dst = tdq;  R = 2048; C = 512;  bid -= 1024; }
  else if (bid < 2304) { src = wkr;  dst = tkr;  R = 2048; C = 128;  bid -= 2048; }
  else if (bid < 2560) { src = wqr;  dst = tqr;  R = 2048; C = 128;  bid -= 2304; }
  else if (bid < 3584) { src = wuk;  dst = tuk;  R = 512;  C = 2048; bid -= 2560; }
  else if (bid < 4608) { src = wuv;  dst = tuv;  R = 512;  C = 2048; bid -= 3584; }
  else if (bid < 5632) { src = wuq;  dst = tuq;  R = 512;  C = 2048; bid -= 4608; }
  else                 { src = wo;   dst = to_;  R = 2048; C = 2048; bid -= 5632; }
  __shared__ float t[32][33];
  int C32 = C >> 5;
  int bx = bid % C32, by = bid / C32;
  int tx = tid & 31, ty = tid >> 5;
  int c0 = bx * 32, r0 = by * 32;
#pragma unroll
  for (int i = 0; i < 32; i += 8)
    t[ty + i][tx] = src[(size_t)(r0 + ty + i) * C + c0 + tx];
  __syncthreads();
#pragma unroll
  for (int i = 0; i < 32; i += 8)
    dst[(size_t)(c0 + ty + i) * R + r0 + tx] = __float2bfloat16(t[tx][ty + i]);
}

// ---------------- rope (both k and q in one launch) ----------------
__global__ void rope_kernel(const bf16* __restrict__ inK, bf16* __restrict__ outK,
                            const bf16* __restrict__ inQ, bf16* __restrict__ outQ) {
  const bf16* in = (blockIdx.y == 0) ? inK : inQ;
  bf16* out = (blockIdx.y == 0) ? outK : outQ;
  int row = blockIdx.x;       // b*2048 + s
  int d = threadIdx.x;        // 0..63
  int pos = row & 2047;
  float x1 = __bfloat162float(in[(size_t)row * 128 + d]);
  float x2 = __bfloat162float(in[(size_t)row * 128 + 64 + d]);
  float inv = exp2f(-(float)d * (13.287712379549449f / 64.0f));  // 10000^(-d/64)
  float ang = (float)pos * inv;
  float sn = sinf(ang), cs = cosf(ang);
  out[(size_t)row * 128 + d]      = __float2bfloat16(x1 * cs - x2 * sn);
  out[(size_t)row * 128 + 64 + d] = __float2bfloat16(x1 * sn + x2 * cs);
}

// ---------------- GEMM: C(MxN) = A(MxK) @ Bt(NxK)^T + bias ----------------
// m97 structure: 128x128 tile, BK=32, 4 waves (2x2), global_load_lds w=16.
// MODE 2 vT region (n0 in [2048,4096)): per-wave LDS-transposed epilogue ->
// coalesced 128B stores (old path: 8B stores at 4KB stride, ~10x write amp).
template <int MODE>
__global__ __launch_bounds__(256) void gemm_bt(
    const bf16* __restrict__ A, const bf16* __restrict__ A2,
    const bf16* __restrict__ Bt,
    const float* __restrict__ b0, const float* __restrict__ b1,
    const float* __restrict__ b2,
    void* __restrict__ C0, void* __restrict__ C1,
    void* __restrict__ C2, void* __restrict__ C3,
    int M, int N, int K) {
  __shared__ bf16 sA[128 * 32];
  __shared__ bf16 sB[128 * 32];
  // per-wave 64x64 transpose buffer, stride 72 (16B-aligned b128 rows), MODE2 only
  __shared__ bf16 trb[(MODE == 2) ? 4 * 64 * 72 : 1];
  const int tid = threadIdx.x, lane = tid & 63, wid = tid >> 6;
  const int l15 = lane & 15, l4 = lane >> 4;
  const int m0 = blockIdx.y * 128, n0 = blockIdx.x * 128;
  const int wm = (wid >> 1) * 64, wn = (wid & 1) * 64;
  f4v acc[4][4] = {};
  const bf16* Ause = (MODE == 2 && n0 >= 4096) ? A2 : A;
  const bf16* gA = Ause + (size_t)m0 * K;
  const bf16* gB = Bt + (size_t)n0 * K;
  const int row = tid >> 2, col = (tid & 3) * 8;
  for (int k0 = 0; k0 < K; k0 += 32) {
    gld16(gA + (size_t)row * K + k0 + col,        sA + tid * 8);
    gld16(gA + (size_t)(row + 64) * K + k0 + col, sA + (tid + 256) * 8);
    gld16(gB + (size_t)row * K + k0 + col,        sB + tid * 8);
    gld16(gB + (size_t)(row + 64) * K + k0 + col, sB + (tid + 256) * 8);
    __syncthreads();
    s8v a[4], b[4];
#pragma unroll
    for (int i = 0; i < 4; i++) a[i] = *(const s8v*)(sA + (wm + i * 16 + l15) * 32 + l4 * 8);
#pragma unroll
    for (int j = 0; j < 4; j++) b[j] = *(const s8v*)(sB + (wn + j * 16 + l15) * 32 + l4 * 8);
#pragma unroll
    for (int i = 0; i < 4; i++)
#pragma unroll
      for (int j = 0; j < 4; j++) acc[i][j] = mfma16(a[i], b[j], acc[i][j]);
    __syncthreads();
  }
  // ---- MODE 2 vT region: per-wave LDS transpose, coalesced stores ----
  if (MODE == 2 && n0 >= 2048 && n0 < 4096) {
    bf16* tb = trb + wid * (64 * 72);
    const int nn0 = n0 - 2048;            // multiple of 128
    const int hh = nn0 >> 7;              // head within vT
    const int bb = m0 >> 11;
    const int ss0 = (m0 & 2047) + wm;     // s base of this wave's quadrant
    // write acc -> tb[d_rel][s_rel] (d_rel = j*16+l15, s_rel = i*16+l4*4+g)
#pragma unroll
    for (int j = 0; j < 4; j++) {
      const float bv = b1[nn0 + wn + j * 16 + l15];
#pragma unroll
      for (int i = 0; i < 4; i++) {
        uint2 w;
        w.x = (unsigned int)f2bfu(acc[i][j][0] + bv) | ((unsigned int)f2bfu(acc[i][j][1] + bv) << 16);
        w.y = (unsigned int)f2bfu(acc[i][j][2] + bv) | ((unsigned int)f2bfu(acc[i][j][3] + bv) << 16);
        *(uint2*)(tb + (j * 16 + l15) * 72 + i * 16 + l4 * 4) = w;
      }
    }
    asm volatile("s_waitcnt lgkmcnt(0)" ::: "memory");
    __builtin_amdgcn_sched_barrier(0);
    // read straight rows (b128) + store: 8 lanes x 16B = 128B contiguous per d-row
    const int dl = lane >> 3, sl = (lane & 7) * 8;
    bf16* dstbase = (bf16*)C1 +
        ((size_t)(bb * 16 + hh) * 128 + wn) * 2048 + ss0;
#pragma unroll
    for (int r = 0; r < 8; r++) {
      int d_rel = r * 8 + dl;
      s8v v = *(const s8v*)(tb + d_rel * 72 + sl);
      *(s8v*)(dstbase + (size_t)d_rel * 2048 + sl) = v;
    }
    return;
  }
  // epilogue. C/D layout: row = l4*4+g, col = l15 (within 16x16 tile)
#pragma unroll
  for (int j = 0; j < 4; j++) {
    const int nb = n0 + wn + j * 16;      // 16-col tile base (uniform per j)
    const int n = nb + l15;
    if (MODE == 3) {
      const float bv = b0[n];
#pragma unroll
      for (int i = 0; i < 4; i++) {
        size_t mb = m0 + wm + i * 16 + l4 * 4;
#pragma unroll
        for (int g = 0; g < 4; g++)
          ((float*)C0)[(mb + g) * (size_t)N + n] = acc[i][j][g] + bv;
      }
    } else if (MODE == 1) {
      const float bv = b0[n];  // 1280-entry concat
      bf16* dst; int stride, nc;
      if (nb < 512)       { dst = (bf16*)C0; stride = 512; nc = n; }
      else if (nb < 1024) { dst = (bf16*)C1; stride = 512; nc = n - 512; }
      else if (nb < 1152) { dst = (bf16*)C2; stride = 128; nc = n - 1024; }
      else                { dst = (bf16*)C3; stride = 128; nc = n - 1152; }
#pragma unroll
      for (int i = 0; i < 4; i++) {
        size_t mb = m0 + wm + i * 16 + l4 * 4;
#pragma unroll
        for (int g = 0; g < 4; g++)
          dst[(mb + g) * (size_t)stride + nc] = __float2bfloat16(acc[i][j][g] + bv);
      }
    } else {  // MODE 2: UK (k_c, nb<2048) | UQ (q_c, nb>=4096); vT handled above
      if (nb < 2048) {
        const float bv = b0[n];
        bf16* dst = (bf16*)C0;
#pragma unroll
        for (int i = 0; i < 4; i++) {
          size_t mb = m0 + wm + i * 16 + l4 * 4;
#pragma unroll
          for (int g = 0; g < 4; g++)
            dst[(mb + g) * (size_t)2048 + n] = __float2bfloat16(acc[i][j][g] + bv);
        }
      } else {
        const float bv = b2[n - 4096];
        bf16* dst = (bf16*)C2;
        int nn = n - 4096;
#pragma unroll
        for (int i = 0; i < 4; i++) {
          size_t mb = m0 + wm + i * 16 + l4 * 4;
#pragma unroll
          for (int g = 0; g < 4; g++)
            dst[(mb + g) * (size_t)2048 + nn] = __float2bfloat16(acc[i][j][g] + bv);
        }
      }
    }
  }
}

// ---------------- flash attention (32x32 MFMA, counted-vmcnt pipeline, XCD swizzle) ----------------
// grid (S/128, B*NH), 256 thr (4 waves; wave owns 32 q-rows). BN=32 keys/iter.
// LDS: TRIPLE-buffered sK/sKr/sVT (8KB each) -> 72KB, 2 blocks/CU. Sync per
// iter: s_waitcnt vmcnt(10) -> raw s_barrier -> sched_barrier(0); stage(t+2)
// + mask(t+1) after -> ~2 compute phases of latency cover (R16-proven).
// XCD swizzle: phys%8 = XCD (round-robin); chunked remap gives each XCD 4
// whole heads -> same-head q-blocks share L2-resident K/V (FETCH was 2.2x
// unique without it).
__global__ __launch_bounds__(256, 2) void flash_attn(
    const bf16* __restrict__ Qc, const bf16* __restrict__ Kc,
    const bf16* __restrict__ Qr, const bf16* __restrict__ Kr,
    const bf16* __restrict__ VT, const int* __restrict__ amask,
    bf16* __restrict__ ctx) {
  const int S = 2048, H = 2048, D = 128;
  __shared__ bf16 sK[3][16 * 32 * 8];
  __shared__ bf16 sKr[3][16 * 32 * 8];
  __shared__ bf16 sVT[3][4 * 128 * 8];

  const int tid = threadIdx.x, lane = tid & 63, wid = tid >> 6;
  const int l31 = lane & 31, hi = lane >> 5;
  // XCD-chunked remap (bijective on 512 = 8*64): XCD c gets heads 4c..4c+3
  const int phys = blockIdx.x + 16 * blockIdx.y;
  const int lid  = (phys & 7) * 64 + (phys >> 3);
  const int qt = lid & 15, bh = lid >> 4;
  const int b = bh >> 4, h = bh & 15;
  const size_t bS = (size_t)b * S;
  const int q0 = qt * 128 + wid * 32;

  // Q fragments (B-operand of swapped QK): q = q0+l31, k(d) = t*16 + hi*8 + j
  s8v qcf[8], qrf[8];
  {
    const bf16* pc = Qc + (bS + q0 + l31) * H + h * D + hi * 8;
    const bf16* pr = Qr + (bS + q0 + l31) * D + hi * 8;
#pragma unroll
    for (int t = 0; t < 8; t++) {
      qcf[t] = *(const s8v*)(pc + t * 16);
      qrf[t] = *(const s8v*)(pr + t * 16);
    }
  }

  f16v oacc[4] = {};   // [dblk]: col=l31 -> d=dblk*32+l31; row(reg)=q pattern
  float lsum = 0.f;
  const float scl = 0.08838834764831845f;  // 1/sqrt(128)

  auto stage = [&](int buf, int kv) {
#pragma unroll
    for (int p = 0; p < 2; p++) {
      int idx = tid + p * 256;
      int key = (idx & 31), dch = (idx >> 5);
      gld16(Kc + (bS + kv + key) * H + h * D + dch * 8, sK[buf] + idx * 8);
      gld16(Kr + (bS + kv + key) * D + dch * 8, sKr[buf] + idx * 8);
      int d = (idx & 127), kch = (idx >> 7);
      gld16(VT + ((size_t)bh * D + d) * S + kv + kch * 8, sVT[buf] + idx * 8);
    }
  };

  const int xaddr = (lane ^ 32) * 4;   // bpermute: partner lane (hi flip)

  // prologue: stage tiles 0,1 + masks for tile 0 (queue: st0[6] mv0[4] st1[6])
  int4 mvC[4], mvN[4];
  stage(0, 0);
#pragma unroll
  for (int g2 = 0; g2 < 4; g2++)
    mvC[g2] = *(const int4*)(amask + bS + 8 * g2 + 4 * hi);
  stage(1, 32);

  for (int it = 0; it < 64; ++it) {
    const int cur = it % 3;
    const int kv0 = it * 32;
    // wait for tile `it` only: outstanding <= st(it)[6]+mv(it)[4]+st(it+1)[6];
    // vmcnt(10) retires the oldest 6 = st(it). Last iter: full drain.
    if (it < 63) asm volatile("s_waitcnt vmcnt(10)" ::: "memory");
    else         asm volatile("s_waitcnt vmcnt(0)" ::: "memory");
    __builtin_amdgcn_s_barrier();
    __builtin_amdgcn_sched_barrier(0);   // no ds_read hoisted above the sync

    // prefetch mask(t+1) then stage(t+2) (order keeps st(t+1) older than both)
    if (it + 1 < 64) {
#pragma unroll
      for (int g2 = 0; g2 < 4; g2++)
        mvN[g2] = *(const int4*)(amask + bS + kv0 + 32 + 8 * g2 + 4 * hi);
    } else {
#pragma unroll
      for (int g2 = 0; g2 < 4; g2++) mvN[g2] = mvC[g2];
    }
    if (it + 2 < 64) stage((it + 2) % 3, kv0 + 64);

    // S^T = Kc.Qc^T + Kr.Qr^T (swapped, 32x32x16): A row=key=l31, k=hi*8+j ->
    // d = t*16+hi*8+j -> sK[dch=2t+hi][key=l31]. Two accs = 2 indep chains.
    f16v scc = {}, scr = {};
    __builtin_amdgcn_s_setprio(1);
#pragma unroll
    for (int t = 0; t < 8; t++) {
      s8v kf = *(const s8v*)(sK[cur] + ((2 * t + hi) * 32 + l31) * 8);
      scc = mfma32(kf, qcf[t], scc);
      s8v rf = *(const s8v*)(sKr[cur] + ((2 * t + hi) * 32 + l31) * 8);
      scr = mfma32(rf, qrf[t], scr);
    }
    __builtin_amdgcn_s_setprio(0);

    // no-max softmax over lane's 16 keys: reg r -> key (r&3)+8*(r>>2)+4*hi.
    // pk2[g2][w] packs keys 8*g2+4*hi+{2w,2w+1} (consecutive).
    unsigned int pk2[4][2];
#pragma unroll
    for (int g2 = 0; g2 < 4; g2++) {
      const int* mm = (const int*)&mvC[g2];
#pragma unroll
      for (int w = 0; w < 2; w++) {
        int r = 4 * g2 + 2 * w;
        float pa = mm[2 * w]     ? __expf((scc[r] + scr[r]) * scl) : 0.f;
        float pb = mm[2 * w + 1] ? __expf((scc[r + 1] + scr[r + 1]) * scl) : 0.f;
        lsum += pa + pb;
        pk2[g2][w] = (unsigned int)f2bfu(pa) | ((unsigned int)f2bfu(pb) << 16);
      }
    }

    // PV A-frag (q=l31, k=16*ks+8*hi+j): own run g2=2ks+hi + partner's same-g2
    // half. Lane passes its g2=2ks+(hi^1) packs; receives partner's g2=2ks+hi.
    s8v pf[2];
#pragma unroll
    for (int ks = 0; ks < 2; ks++) {
      int passA = hi ? (int)pk2[2 * ks][0] : (int)pk2[2 * ks + 1][0];
      int passB = hi ? (int)pk2[2 * ks][1] : (int)pk2[2 * ks + 1][1];
      int recvA = __builtin_amdgcn_ds_bpermute(xaddr, passA);
      int recvB = __builtin_amdgcn_ds_bpermute(xaddr, passB);
      union { int w[4]; s8v v; } u;
      u.w[0] = hi ? recvA : (int)pk2[2 * ks][0];
      u.w[1] = hi ? recvB : (int)pk2[2 * ks][1];
      u.w[2] = hi ? (int)pk2[2 * ks + 1][0] : recvA;
      u.w[3] = hi ? (int)pk2[2 * ks + 1][1] : recvB;
      pf[ks] = u.v;
    }

    // O += P @ V (32x32x16): B col=l31=d, k=hi*8+j -> key=16ks+8hi+j ->
    // sVT[kch=2ks+hi][d]. 4 indep acc chains (dblk), depth 2.
    __builtin_amdgcn_s_setprio(1);
#pragma unroll
    for (int dblk = 0; dblk < 4; dblk++) {
      s8v vf0 = *(const s8v*)(sVT[cur] + ((0 + hi) * 128 + dblk * 32 + l31) * 8);
      oacc[dblk] = mfma32(pf[0], vf0, oacc[dblk]);
      s8v vf1 = *(const s8v*)(sVT[cur] + ((2 + hi) * 128 + dblk * 32 + l31) * 8);
      oacc[dblk] = mfma32(pf[1], vf1, oacc[dblk]);
    }
    __builtin_amdgcn_s_setprio(0);

#pragma unroll
    for (int g2 = 0; g2 < 4; g2++) mvC[g2] = mvN[g2];
  }

  // row sums: lane's lsum covers 16 of 32 keys/iter for q=l31; partner (^32)
  // has the rest -> one xor reduce gives the full sum per q=l31.
  float s = lsum;
  s += __shfl_xor(s, 32, 64);
  float inv[16];
#pragma unroll
  for (int g = 0; g < 16; g++) {
    int ql = (g & 3) + 8 * (g >> 2) + 4 * hi;   // oacc reg g's q (0..31)
    inv[g] = 1.0f / __shfl(s, ql, 64);
  }

  // normalize + store ctx (B,S,H): oacc[dblk][g] -> q=pattern, d=dblk*32+l31
#pragma unroll
  for (int dblk = 0; dblk < 4; dblk++)
#pragma unroll
    for (int g = 0; g < 16; g++) {
      int qrow = q0 + (g & 3) + 8 * (g >> 2) + 4 * hi;
      ctx[(bS + qrow) * H + h * D + dblk * 32 + l31] =
          __float2bfloat16(oacc[dblk][g] * inv[g]);
    }
}

// ---------------- launch ----------------
extern "C" void kernel_launch(void* const* d_in, const int* in_sizes, int n_in,
                              void* d_out, int out_size, void* d_ws, size_t ws_size,
                              hipStream_t stream) {
  const float* hs    = (const float*)d_in[0];
  const int*   amask = (const int*)d_in[1];
  const float* W_DKV = (const float*)d_in[2];  const float* b_DKV = (const float*)d_in[3];
  const float* W_DQ  = (const float*)d_in[4];  const float* b_DQ  = (const float*)d_in[5];
  const float* W_UK  = (const float*)d_in[6];  const float* b_UK  = (const float*)d_in[7];
  const float* W_UV  = (const float*)d_in[8];  const float* b_UV  = (const float*)d_in[9];
  const float* W_UQ  = (const float*)d_in[10]; const float* b_UQ  = (const float*)d_in[11];
  const float* W_KR  = (const float*)d_in[12]; const float* b_KR  = (const float*)d_in[13];
  const float* W_QR  = (const float*)d_in[14]; const float* b_QR  = (const float*)d_in[15];
  const float* W_O   = (const float*)d_in[16]; const float* b_O   = (const float*)d_in[17];

  char* wsb = (char*)d_ws;
  size_t off = 0;
  auto allocB = [&](size_t bytes) {
    void* p = wsb + off; off = (off + bytes + 255) & ~(size_t)255; return p;
  };
  float* bcat  = (float*)allocB(1280 * 4);
  bf16* hsb    = (bf16*)allocB((size_t)4096 * 2048 * 2);
  bf16* wt_dkv = (bf16*)allocB((size_t)512 * 2048 * 2);
  bf16* wt_dq  = (bf16*)allocB((size_t)512 * 2048 * 2);
  bf16* wt_kr  = (bf16*)allocB((size_t)128 * 2048 * 2);
  bf16* wt_qr  = (bf16*)allocB((size_t)128 * 2048 * 2);
  // wt_uk|wt_uv|wt_uq MUST stay contiguous (single Bt for the merged GEMM):
  bf16* wt_uk  = (bf16*)allocB((size_t)2048 * 512 * 2);
  bf16* wt_uv  = (bf16*)allocB((size_t)2048 * 512 * 2);
  bf16* wt_uq  = (bf16*)allocB((size_t)2048 * 512 * 2);
  bf16* wt_o   = (bf16*)allocB((size_t)2048 * 2048 * 2);
  bf16* c_kv   = (bf16*)allocB((size_t)4096 * 512 * 2);
  bf16* c_q    = (bf16*)allocB((size_t)4096 * 512 * 2);
  bf16* krl    = (bf16*)allocB((size_t)4096 * 128 * 2);
  bf16* qrl    = (bf16*)allocB((size_t)4096 * 128 * 2);
  bf16* k_r    = (bf16*)allocB((size_t)4096 * 128 * 2);
  bf16* q_r    = (bf16*)allocB((size_t)4096 * 128 * 2);
  bf16* k_c    = (bf16*)allocB((size_t)4096 * 2048 * 2);
  bf16* q_c    = (bf16*)allocB((size_t)4096 * 2048 * 2);
  bf16* vT     = (bf16*)allocB((size_t)4096 * 2048 * 2);
  bf16* ctx    = (bf16*)allocB((size_t)4096 * 2048 * 2);
  (void)wt_uv; (void)wt_uq;

  // one-shot ingest: 4096 hs-convert + 1 bias-concat + 9728 transpose tiles
  prep<<<13825, 256, 0, stream>>>(hs, hsb,
      b_DKV, b_DQ, b_KR, b_QR, bcat,
      W_DKV, wt_dkv, W_DQ, wt_dq, W_KR, wt_kr, W_QR, wt_qr,
      W_UK, wt_uk, W_UV, wt_uv, W_UQ, wt_uq, W_O, wt_o);

  // fused projections: N = 512|512|128|128 = 1280, K = 2048
  gemm_bt<1><<<dim3(10, 32), 256, 0, stream>>>(
      hsb, nullptr, wt_dkv, bcat, nullptr, nullptr,
      c_kv, c_q, krl, qrl, 4096, 1280, 2048);
  rope_kernel<<<dim3(4096, 2), 64, 0, stream>>>(krl, k_r, qrl, q_r);

  // merged UK|UV|UQ: N = 2048*3 = 6144, K = 512 (A = c_kv for n<4096, c_q above)
  gemm_bt<2><<<dim3(48, 32), 256, 0, stream>>>(
      c_kv, c_q, wt_uk, b_UK, b_UV, b_UQ,
      k_c, vT, q_c, nullptr, 4096, 6144, 512);

  // attention: grid (2048/128, 32) = 512 blocks, 2 blocks/CU (72KB LDS)
  flash_attn<<<dim3(16, 32), 256, 0, stream>>>(q_c, k_c, q_r, k_r, vT, amask, ctx);

  // output projection (fp32 out)
  gemm_bt<3><<<dim3(16, 32), 256, 0, stream>>>(
      ctx, nullptr, wt_o, b_O, nullptr, nullptr,
      d_out, nullptr, nullptr, nullptr, 4096, 2048, 2048);
}

// Round 9
// 430.724 us; speedup vs baseline: 1.1734x; 1.0282x over previous
//
#include <hip/hip_runtime.h>
#include <hip/hip_bf16.h>
#include <stdint.h>

// MLA forward: B=2,S=2048,H=2048,NH=16,D=128,LAT=512. Inputs fp32 (R3-proven).
// R18: GEMM occupancy + locality (flash = R17, frozen as control):
// (1) gemm1 tile 128x64 (NT template): was grid 10x32=320 blocks = 1.25/CU --
//     no multi-block overlap, full staging latency every K-step. Now 640
//     blocks = 2.5/CU (m97-class efficiency needs ~3 resident blocks).
// (2) XCD-chunked block swizzle in all gemm launches (grids 640/1536/512 all
//     %8==0): x-major neighbors (same A-panel) -> same XCD L2 (T1; flash's
//     swizzle cut FETCH 5x in R17).
typedef __hip_bfloat16 bf16;
typedef __attribute__((ext_vector_type(8))) short s8v;    // 8 x bf16 (4 VGPRs)
typedef __attribute__((ext_vector_type(4))) float f4v;    // 16x16 accum
typedef __attribute__((ext_vector_type(16))) float f16v;  // 32x32 accum

__device__ __forceinline__ void gld16(const bf16* g, bf16* l) {
  __builtin_amdgcn_global_load_lds(
      (__attribute__((address_space(1))) unsigned int*)g,
      (__attribute__((address_space(3))) unsigned int*)l, 16, 0, 0);
}

__device__ __forceinline__ f4v mfma16(s8v a, s8v b, f4v c) {
  return __builtin_amdgcn_mfma_f32_16x16x32_bf16(a, b, c, 0, 0, 0);
}

__device__ __forceinline__ f16v mfma32(s8v a, s8v b, f16v c) {
  return __builtin_amdgcn_mfma_f32_32x32x16_bf16(a, b, c, 0, 0, 0);
}

__device__ __forceinline__ unsigned short f2bfu(float f) {
  union { bf16 h; unsigned short u; } cv;
  cv.h = __float2bfloat16(f);
  return cv.u;
}

// ---------------- prep: hs fp32->bf16 + 8 weight transposes + bias concat ----------------
__global__ __launch_bounds__(256) void prep(
    const float* __restrict__ hs, bf16* __restrict__ hsb,
    const float* __restrict__ bdkv, const float* __restrict__ bdq,
    const float* __restrict__ bkr, const float* __restrict__ bqr,
    float* __restrict__ bcat,
    const float* __restrict__ wdkv, bf16* __restrict__ tdkv,
    const float* __restrict__ wdq,  bf16* __restrict__ tdq,
    const float* __restrict__ wkr,  bf16* __restrict__ tkr,
    const float* __restrict__ wqr,  bf16* __restrict__ tqr,
    const float* __restrict__ wuk,  bf16* __restrict__ tuk,
    const float* __restrict__ wuv,  bf16* __restrict__ tuv,
    const float* __restrict__ wuq,  bf16* __restrict__ tuq,
    const float* __restrict__ wo,   bf16* __restrict__ to_) {
  int bid = blockIdx.x;
  int tid = threadIdx.x;
  if (bid < 4096) {
    int i = (bid * 256 + tid) * 8;
    union { s8v v; unsigned short u[8]; } pk;
#pragma unroll
    for (int j = 0; j < 8; j++) pk.u[j] = f2bfu(hs[i + j]);
    *(s8v*)(hsb + i) = pk.v;
    return;
  }
  if (bid == 4096) {
#pragma unroll
    for (int p = 0; p < 5; p++) {
      int i = tid + p * 256;
      float v;
      if (i < 512)       v = bdkv[i];
      else if (i < 1024) v = bdq[i - 512];
      else if (i < 1152) v = bkr[i - 1024];
      else               v = bqr[i - 1152];
      bcat[i] = v;
    }
    return;
  }
  bid -= 4097;
  const float* src; bf16* dst; int R, C;
  if      (bid < 1024) { src = wdkv; dst = tdkv; R = 2048; C = 512;  }
  else if (bid < 2048) { src = wdq;  dst = tdq;  R = 2048; C = 512;  bid -= 1024; }
  else if (bid < 2304) { src = wkr;  dst = tkr;  R = 2048; C = 128;  bid -= 2048; }
  else if (bid < 2560) { src = wqr;  dst = tqr;  R = 2048; C = 128;  bid -= 2304; }
  else if (bid < 3584) { src = wuk;  dst = tuk;  R = 512;  C = 2048; bid -= 2560; }
  else if (bid < 4608) { src = wuv;  dst = tuv;  R = 512;  C = 2048; bid -= 3584; }
  else if (bid < 5632) { src = wuq;  dst = tuq;  R = 512;  C = 2048; bid -= 4608; }
  else                 { src = wo;   dst = to_;  R = 2048; C = 2048; bid -= 5632; }
  __shared__ float t[32][33];
  int C32 = C >> 5;
  int bx = bid % C32, by = bid / C32;
  int tx = tid & 31, ty = tid >> 5;
  int c0 = bx * 32, r0 = by * 32;
#pragma unroll
  for (int i = 0; i < 32; i += 8)
    t[ty + i][tx] = src[(size_t)(r0 + ty + i) * C + c0 + tx];
  __syncthreads();
#pragma unroll
  for (int i = 0; i < 32; i += 8)
    dst[(size_t)(c0 + ty + i) * R + r0 + tx] = __float2bfloat16(t[tx][ty + i]);
}

// ---------------- rope (both k and q in one launch) ----------------
__global__ void rope_kernel(const bf16* __restrict__ inK, bf16* __restrict__ outK,
                            const bf16* __restrict__ inQ, bf16* __restrict__ outQ) {
  const bf16* in = (blockIdx.y == 0) ? inK : inQ;
  bf16* out = (blockIdx.y == 0) ? outK : outQ;
  int row = blockIdx.x;       // b*2048 + s
  int d = threadIdx.x;        // 0..63
  int pos = row & 2047;
  float x1 = __bfloat162float(in[(size_t)row * 128 + d]);
  float x2 = __bfloat162float(in[(size_t)row * 128 + 64 + d]);
  float inv = exp2f(-(float)d * (13.287712379549449f / 64.0f));  // 10000^(-d/64)
  float ang = (float)pos * inv;
  float sn = sinf(ang), cs = cosf(ang);
  out[(size_t)row * 128 + d]      = __float2bfloat16(x1 * cs - x2 * sn);
  out[(size_t)row * 128 + 64 + d] = __float2bfloat16(x1 * sn + x2 * cs);
}

// ---------------- GEMM: C(MxN) = A(MxK) @ Bt(NxK)^T + bias ----------------
// m97 structure: 128xNT tile, BK=32, 4 waves (2x2), global_load_lds w=16.
// NT=128 (MODE2/3) or 64 (MODE1: doubles block count for occupancy overlap).
// XCD-chunked block swizzle (grid %8==0): x-major neighbors -> same XCD L2.
template <int MODE, int NT>
__global__ __launch_bounds__(256) void gemm_bt(
    const bf16* __restrict__ A, const bf16* __restrict__ A2,
    const bf16* __restrict__ Bt,
    const float* __restrict__ b0, const float* __restrict__ b1,
    const float* __restrict__ b2,
    void* __restrict__ C0, void* __restrict__ C1,
    void* __restrict__ C2, void* __restrict__ C3,
    int M, int N, int K) {
  constexpr int WN = NT / 2;        // per-wave n extent
  constexpr int NJ = WN / 16;       // per-wave 16-col tiles
  __shared__ bf16 sA[128 * 32];
  __shared__ bf16 sB[NT * 32];
  // per-wave 64x64 transpose buffer, stride 72 (16B-aligned b128 rows), MODE2 only
  __shared__ bf16 trb[(MODE == 2) ? 4 * 64 * 72 : 1];
  const int tid = threadIdx.x, lane = tid & 63, wid = tid >> 6;
  const int l15 = lane & 15, l4 = lane >> 4;
  // XCD-chunked swizzle (bijective when nwg%8==0)
  const int nwg = gridDim.x * gridDim.y;
  int bid = blockIdx.x + gridDim.x * blockIdx.y;
  bid = (bid & 7) * (nwg >> 3) + (bid >> 3);
  const int m0 = (bid / gridDim.x) * 128, n0 = (bid % gridDim.x) * NT;
  const int wm = (wid >> 1) * 64, wn = (wid & 1) * WN;
  f4v acc[4][NJ] = {};
  const bf16* Ause = (MODE == 2 && n0 >= 4096) ? A2 : A;
  const bf16* gA = Ause + (size_t)m0 * K;
  const bf16* gB = Bt + (size_t)n0 * K;
  const int row = tid >> 2, col = (tid & 3) * 8;
  for (int k0 = 0; k0 < K; k0 += 32) {
    gld16(gA + (size_t)row * K + k0 + col,        sA + tid * 8);
    gld16(gA + (size_t)(row + 64) * K + k0 + col, sA + (tid + 256) * 8);
    gld16(gB + (size_t)row * K + k0 + col,        sB + tid * 8);
    if (NT == 128)
      gld16(gB + (size_t)(row + 64) * K + k0 + col, sB + (tid + 256) * 8);
    __syncthreads();
    s8v a[4], b[NJ];
#pragma unroll
    for (int i = 0; i < 4; i++) a[i] = *(const s8v*)(sA + (wm + i * 16 + l15) * 32 + l4 * 8);
#pragma unroll
    for (int j = 0; j < NJ; j++) b[j] = *(const s8v*)(sB + (wn + j * 16 + l15) * 32 + l4 * 8);
#pragma unroll
    for (int i = 0; i < 4; i++)
#pragma unroll
      for (int j = 0; j < NJ; j++) acc[i][j] = mfma16(a[i], b[j], acc[i][j]);
    __syncthreads();
  }
  // ---- MODE 2 vT region: per-wave LDS transpose, coalesced stores ----
  if (MODE == 2 && n0 >= 2048 && n0 < 4096) {
    bf16* tb = trb + wid * (64 * 72);
    const int nn0 = n0 - 2048;            // multiple of 128
    const int hh = nn0 >> 7;              // head within vT
    const int bb = m0 >> 11;
    const int ss0 = (m0 & 2047) + wm;     // s base of this wave's quadrant
    // write acc -> tb[d_rel][s_rel] (d_rel = j*16+l15, s_rel = i*16+l4*4+g)
#pragma unroll
    for (int j = 0; j < NJ; j++) {
      const float bv = b1[nn0 + wn + j * 16 + l15];
#pragma unroll
      for (int i = 0; i < 4; i++) {
        uint2 w;
        w.x = (unsigned int)f2bfu(acc[i][j][0] + bv) | ((unsigned int)f2bfu(acc[i][j][1] + bv) << 16);
        w.y = (unsigned int)f2bfu(acc[i][j][2] + bv) | ((unsigned int)f2bfu(acc[i][j][3] + bv) << 16);
        *(uint2*)(tb + (j * 16 + l15) * 72 + i * 16 + l4 * 4) = w;
      }
    }
    asm volatile("s_waitcnt lgkmcnt(0)" ::: "memory");
    __builtin_amdgcn_sched_barrier(0);
    // read straight rows (b128) + store: 8 lanes x 16B = 128B contiguous per d-row
    const int dl = lane >> 3, sl = (lane & 7) * 8;
    bf16* dstbase = (bf16*)C1 +
        ((size_t)(bb * 16 + hh) * 128 + wn) * 2048 + ss0;
#pragma unroll
    for (int r = 0; r < 8; r++) {
      int d_rel = r * 8 + dl;
      s8v v = *(const s8v*)(tb + d_rel * 72 + sl);
      *(s8v*)(dstbase + (size_t)d_rel * 2048 + sl) = v;
    }
    return;
  }
  // epilogue. C/D layout: row = l4*4+g, col = l15 (within 16x16 tile)
#pragma unroll
  for (int j = 0; j < NJ; j++) {
    const int nb = n0 + wn + j * 16;      // 16-col tile base (uniform per j)
    const int n = nb + l15;
    if (MODE == 3) {
      const float bv = b0[n];
#pragma unroll
      for (int i = 0; i < 4; i++) {
        size_t mb = m0 + wm + i * 16 + l4 * 4;
#pragma unroll
        for (int g = 0; g < 4; g++)
          ((float*)C0)[(mb + g) * (size_t)N + n] = acc[i][j][g] + bv;
      }
    } else if (MODE == 1) {
      const float bv = b0[n];  // 1280-entry concat
      bf16* dst; int stride, nc;
      if (nb < 512)       { dst = (bf16*)C0; stride = 512; nc = n; }
      else if (nb < 1024) { dst = (bf16*)C1; stride = 512; nc = n - 512; }
      else if (nb < 1152) { dst = (bf16*)C2; stride = 128; nc = n - 1024; }
      else                { dst = (bf16*)C3; stride = 128; nc = n - 1152; }
#pragma unroll
      for (int i = 0; i < 4; i++) {
        size_t mb = m0 + wm + i * 16 + l4 * 4;
#pragma unroll
        for (int g = 0; g < 4; g++)
          dst[(mb + g) * (size_t)stride + nc] = __float2bfloat16(acc[i][j][g] + bv);
      }
    } else {  // MODE 2: UK (k_c, nb<2048) | UQ (q_c, nb>=4096); vT handled above
      if (nb < 2048) {
        const float bv = b0[n];
        bf16* dst = (bf16*)C0;
#pragma unroll
        for (int i = 0; i < 4; i++) {
          size_t mb = m0 + wm + i * 16 + l4 * 4;
#pragma unroll
          for (int g = 0; g < 4; g++)
            dst[(mb + g) * (size_t)2048 + n] = __float2bfloat16(acc[i][j][g] + bv);
        }
      } else {
        const float bv = b2[n - 4096];
        bf16* dst = (bf16*)C2;
        int nn = n - 4096;
#pragma unroll
        for (int i = 0; i < 4; i++) {
          size_t mb = m0 + wm + i * 16 + l4 * 4;
#pragma unroll
          for (int g = 0; g < 4; g++)
            dst[(mb + g) * (size_t)2048 + nn] = __float2bfloat16(acc[i][j][g] + bv);
        }
      }
    }
  }
}

// ---------------- flash attention (32x32 MFMA, counted-vmcnt pipeline, XCD swizzle) ----------------
// grid (S/128, B*NH), 256 thr (4 waves; wave owns 32 q-rows). BN=32 keys/iter.
// LDS: TRIPLE-buffered sK/sKr/sVT (8KB each) -> 72KB, 2 blocks/CU. Sync per
// iter: s_waitcnt vmcnt(10) -> raw s_barrier -> sched_barrier(0); stage(t+2)
// + mask(t+1) after -> ~2 compute phases of latency cover (R16-proven).
// XCD swizzle: chunked remap gives each XCD 4 whole heads (R17: FETCH 5x cut).
__global__ __launch_bounds__(256, 2) void flash_attn(
    const bf16* __restrict__ Qc, const bf16* __restrict__ Kc,
    const bf16* __restrict__ Qr, const bf16* __restrict__ Kr,
    const bf16* __restrict__ VT, const int* __restrict__ amask,
    bf16* __restrict__ ctx) {
  const int S = 2048, H = 2048, D = 128;
  __shared__ bf16 sK[3][16 * 32 * 8];
  __shared__ bf16 sKr[3][16 * 32 * 8];
  __shared__ bf16 sVT[3][4 * 128 * 8];

  const int tid = threadIdx.x, lane = tid & 63, wid = tid >> 6;
  const int l31 = lane & 31, hi = lane >> 5;
  // XCD-chunked remap (bijective on 512 = 8*64): XCD c gets heads 4c..4c+3
  const int phys = blockIdx.x + 16 * blockIdx.y;
  const int lid  = (phys & 7) * 64 + (phys >> 3);
  const int qt = lid & 15, bh = lid >> 4;
  const int b = bh >> 4, h = bh & 15;
  const size_t bS = (size_t)b * S;
  const int q0 = qt * 128 + wid * 32;

  // Q fragments (B-operand of swapped QK): q = q0+l31, k(d) = t*16 + hi*8 + j
  s8v qcf[8], qrf[8];
  {
    const bf16* pc = Qc + (bS + q0 + l31) * H + h * D + hi * 8;
    const bf16* pr = Qr + (bS + q0 + l31) * D + hi * 8;
#pragma unroll
    for (int t = 0; t < 8; t++) {
      qcf[t] = *(const s8v*)(pc + t * 16);
      qrf[t] = *(const s8v*)(pr + t * 16);
    }
  }

  f16v oacc[4] = {};   // [dblk]: col=l31 -> d=dblk*32+l31; row(reg)=q pattern
  float lsum = 0.f;
  const float scl = 0.08838834764831845f;  // 1/sqrt(128)

  auto stage = [&](int buf, int kv) {
#pragma unroll
    for (int p = 0; p < 2; p++) {
      int idx = tid + p * 256;
      int key = (idx & 31), dch = (idx >> 5);
      gld16(Kc + (bS + kv + key) * H + h * D + dch * 8, sK[buf] + idx * 8);
      gld16(Kr + (bS + kv + key) * D + dch * 8, sKr[buf] + idx * 8);
      int d = (idx & 127), kch = (idx >> 7);
      gld16(VT + ((size_t)bh * D + d) * S + kv + kch * 8, sVT[buf] + idx * 8);
    }
  };

  const int xaddr = (lane ^ 32) * 4;   // bpermute: partner lane (hi flip)

  // prologue: stage tiles 0,1 + masks for tile 0 (queue: st0[6] mv0[4] st1[6])
  int4 mvC[4], mvN[4];
  stage(0, 0);
#pragma unroll
  for (int g2 = 0; g2 < 4; g2++)
    mvC[g2] = *(const int4*)(amask + bS + 8 * g2 + 4 * hi);
  stage(1, 32);

  for (int it = 0; it < 64; ++it) {
    const int cur = it % 3;
    const int kv0 = it * 32;
    // wait for tile `it` only: outstanding <= st(it)[6]+mv(it)[4]+st(it+1)[6];
    // vmcnt(10) retires the oldest 6 = st(it). Last iter: full drain.
    if (it < 63) asm volatile("s_waitcnt vmcnt(10)" ::: "memory");
    else         asm volatile("s_waitcnt vmcnt(0)" ::: "memory");
    __builtin_amdgcn_s_barrier();
    __builtin_amdgcn_sched_barrier(0);   // no ds_read hoisted above the sync

    // prefetch mask(t+1) then stage(t+2) (order keeps st(t+1) older than both)
    if (it + 1 < 64) {
#pragma unroll
      for (int g2 = 0; g2 < 4; g2++)
        mvN[g2] = *(const int4*)(amask + bS + kv0 + 32 + 8 * g2 + 4 * hi);
    } else {
#pragma unroll
      for (int g2 = 0; g2 < 4; g2++) mvN[g2] = mvC[g2];
    }
    if (it + 2 < 64) stage((it + 2) % 3, kv0 + 64);

    // S^T = Kc.Qc^T + Kr.Qr^T (swapped, 32x32x16): A row=key=l31, k=hi*8+j ->
    // d = t*16+hi*8+j -> sK[dch=2t+hi][key=l31]. Two accs = 2 indep chains.
    f16v scc = {}, scr = {};
    __builtin_amdgcn_s_setprio(1);
#pragma unroll
    for (int t = 0; t < 8; t++) {
      s8v kf = *(const s8v*)(sK[cur] + ((2 * t + hi) * 32 + l31) * 8);
      scc = mfma32(kf, qcf[t], scc);
      s8v rf = *(const s8v*)(sKr[cur] + ((2 * t + hi) * 32 + l31) * 8);
      scr = mfma32(rf, qrf[t], scr);
    }
    __builtin_amdgcn_s_setprio(0);

    // no-max softmax over lane's 16 keys: reg r -> key (r&3)+8*(r>>2)+4*hi.
    // pk2[g2][w] packs keys 8*g2+4*hi+{2w,2w+1} (consecutive).
    unsigned int pk2[4][2];
#pragma unroll
    for (int g2 = 0; g2 < 4; g2++) {
      const int* mm = (const int*)&mvC[g2];
#pragma unroll
      for (int w = 0; w < 2; w++) {
        int r = 4 * g2 + 2 * w;
        float pa = mm[2 * w]     ? __expf((scc[r] + scr[r]) * scl) : 0.f;
        float pb = mm[2 * w + 1] ? __expf((scc[r + 1] + scr[r + 1]) * scl) : 0.f;
        lsum += pa + pb;
        pk2[g2][w] = (unsigned int)f2bfu(pa) | ((unsigned int)f2bfu(pb) << 16);
      }
    }

    // PV A-frag (q=l31, k=16*ks+8*hi+j): own run g2=2ks+hi + partner's same-g2
    // half. Lane passes its g2=2ks+(hi^1) packs; receives partner's g2=2ks+hi.
    s8v pf[2];
#pragma unroll
    for (int ks = 0; ks < 2; ks++) {
      int passA = hi ? (int)pk2[2 * ks][0] : (int)pk2[2 * ks + 1][0];
      int passB = hi ? (int)pk2[2 * ks][1] : (int)pk2[2 * ks + 1][1];
      int recvA = __builtin_amdgcn_ds_bpermute(xaddr, passA);
      int recvB = __builtin_amdgcn_ds_bpermute(xaddr, passB);
      union { int w[4]; s8v v; } u;
      u.w[0] = hi ? recvA : (int)pk2[2 * ks][0];
      u.w[1] = hi ? recvB : (int)pk2[2 * ks][1];
      u.w[2] = hi ? (int)pk2[2 * ks + 1][0] : recvA;
      u.w[3] = hi ? (int)pk2[2 * ks + 1][1] : recvB;
      pf[ks] = u.v;
    }

    // O += P @ V (32x32x16): B col=l31=d, k=hi*8+j -> key=16ks+8hi+j ->
    // sVT[kch=2ks+hi][d]. 4 indep acc chains (dblk), depth 2.
    __builtin_amdgcn_s_setprio(1);
#pragma unroll
    for (int dblk = 0; dblk < 4; dblk++) {
      s8v vf0 = *(const s8v*)(sVT[cur] + ((0 + hi) * 128 + dblk * 32 + l31) * 8);
      oacc[dblk] = mfma32(pf[0], vf0, oacc[dblk]);
      s8v vf1 = *(const s8v*)(sVT[cur] + ((2 + hi) * 128 + dblk * 32 + l31) * 8);
      oacc[dblk] = mfma32(pf[1], vf1, oacc[dblk]);
    }
    __builtin_amdgcn_s_setprio(0);

#pragma unroll
    for (int g2 = 0; g2 < 4; g2++) mvC[g2] = mvN[g2];
  }

  // row sums: lane's lsum covers 16 of 32 keys/iter for q=l31; partner (^32)
  // has the rest -> one xor reduce gives the full sum per q=l31.
  float s = lsum;
  s += __shfl_xor(s, 32, 64);
  float inv[16];
#pragma unroll
  for (int g = 0; g < 16; g++) {
    int ql = (g & 3) + 8 * (g >> 2) + 4 * hi;   // oacc reg g's q (0..31)
    inv[g] = 1.0f / __shfl(s, ql, 64);
  }

  // normalize + store ctx (B,S,H): oacc[dblk][g] -> q=pattern, d=dblk*32+l31
#pragma unroll
  for (int dblk = 0; dblk < 4; dblk++)
#pragma unroll
    for (int g = 0; g < 16; g++) {
      int qrow = q0 + (g & 3) + 8 * (g >> 2) + 4 * hi;
      ctx[(bS + qrow) * H + h * D + dblk * 32 + l31] =
          __float2bfloat16(oacc[dblk][g] * inv[g]);
    }
}

// ---------------- launch ----------------
extern "C" void kernel_launch(void* const* d_in, const int* in_sizes, int n_in,
                              void* d_out, int out_size, void* d_ws, size_t ws_size,
                              hipStream_t stream) {
  const float* hs    = (const float*)d_in[0];
  const int*   amask = (const int*)d_in[1];
  const float* W_DKV = (const float*)d_in[2];  const float* b_DKV = (const float*)d_in[3];
  const float* W_DQ  = (const float*)d_in[4];  const float* b_DQ  = (const float*)d_in[5];
  const float* W_UK  = (const float*)d_in[6];  const float* b_UK  = (const float*)d_in[7];
  const float* W_UV  = (const float*)d_in[8];  const float* b_UV  = (const float*)d_in[9];
  const float* W_UQ  = (const float*)d_in[10]; const float* b_UQ  = (const float*)d_in[11];
  const float* W_KR  = (const float*)d_in[12]; const float* b_KR  = (const float*)d_in[13];
  const float* W_QR  = (const float*)d_in[14]; const float* b_QR  = (const float*)d_in[15];
  const float* W_O   = (const float*)d_in[16]; const float* b_O   = (const float*)d_in[17];

  char* wsb = (char*)d_ws;
  size_t off = 0;
  auto allocB = [&](size_t bytes) {
    void* p = wsb + off; off = (off + bytes + 255) & ~(size_t)255; return p;
  };
  float* bcat  = (float*)allocB(1280 * 4);
  bf16* hsb    = (bf16*)allocB((size_t)4096 * 2048 * 2);
  bf16* wt_dkv = (bf16*)allocB((size_t)512 * 2048 * 2);
  bf16* wt_dq  = (bf16*)allocB((size_t)512 * 2048 * 2);
  bf16* wt_kr  = (bf16*)allocB((size_t)128 * 2048 * 2);
  bf16* wt_qr  = (bf16*)allocB((size_t)128 * 2048 * 2);
  // wt_uk|wt_uv|wt_uq MUST stay contiguous (single Bt for the merged GEMM):
  bf16* wt_uk  = (bf16*)allocB((size_t)2048 * 512 * 2);
  bf16* wt_uv  = (bf16*)allocB((size_t)2048 * 512 * 2);
  bf16* wt_uq  = (bf16*)allocB((size_t)2048 * 512 * 2);
  bf16* wt_o   = (bf16*)allocB((size_t)2048 * 2048 * 2);
  bf16* c_kv   = (bf16*)allocB((size_t)4096 * 512 * 2);
  bf16* c_q    = (bf16*)allocB((size_t)4096 * 512 * 2);
  bf16* krl    = (bf16*)allocB((size_t)4096 * 128 * 2);
  bf16* qrl    = (bf16*)allocB((size_t)4096 * 128 * 2);
  bf16* k_r    = (bf16*)allocB((size_t)4096 * 128 * 2);
  bf16* q_r    = (bf16*)allocB((size_t)4096 * 128 * 2);
  bf16* k_c    = (bf16*)allocB((size_t)4096 * 2048 * 2);
  bf16* q_c    = (bf16*)allocB((size_t)4096 * 2048 * 2);
  bf16* vT     = (bf16*)allocB((size_t)4096 * 2048 * 2);
  bf16* ctx    = (bf16*)allocB((size_t)4096 * 2048 * 2);
  (void)wt_uv; (void)wt_uq;

  // one-shot ingest: 4096 hs-convert + 1 bias-concat + 9728 transpose tiles
  prep<<<13825, 256, 0, stream>>>(hs, hsb,
      b_DKV, b_DQ, b_KR, b_QR, bcat,
      W_DKV, wt_dkv, W_DQ, wt_dq, W_KR, wt_kr, W_QR, wt_qr,
      W_UK, wt_uk, W_UV, wt_uv, W_UQ, wt_uq, W_O, wt_o);

  // fused projections: N = 512|512|128|128 = 1280, K = 2048.
  // NT=64 tile -> 640 blocks (2.5/CU; was 320 = 1.25/CU, no overlap)
  gemm_bt<1, 64><<<dim3(20, 32), 256, 0, stream>>>(
      hsb, nullptr, wt_dkv, bcat, nullptr, nullptr,
      c_kv, c_q, krl, qrl, 4096, 1280, 2048);
  rope_kernel<<<dim3(4096, 2), 64, 0, stream>>>(krl, k_r, qrl, q_r);

  // merged UK|UV|UQ: N = 2048*3 = 6144, K = 512 (A = c_kv for n<4096, c_q above)
  gemm_bt<2, 128><<<dim3(48, 32), 256, 0, stream>>>(
      c_kv, c_q, wt_uk, b_UK, b_UV, b_UQ,
      k_c, vT, q_c, nullptr, 4096, 6144, 512);

  // attention: grid (2048/128, 32) = 512 blocks, 2 blocks/CU (72KB LDS)
  flash_attn<<<dim3(16, 32), 256, 0, stream>>>(q_c, k_c, q_r, k_r, vT, amask, ctx);

  // output projection (fp32 out)
  gemm_bt<3, 128><<<dim3(16, 32), 256, 0, stream>>>(
      ctx, nullptr, wt_o, b_O, nullptr, nullptr,
      d_out, nullptr, nullptr, nullptr, 4096, 2048, 2048);
}

// Round 10
// 406.944 us; speedup vs baseline: 1.2420x; 1.0584x over previous
//
#include <hip/hip_runtime.h>
#include <hip/hip_bf16.h>
#include <stdint.h>

// MLA forward: B=2,S=2048,H=2048,NH=16,D=128,LAT=512. Inputs fp32 (R3-proven).
// R19: transfer R16's counted-vmcnt pipeline (T3/T4) to gemm_bt. The GEMM
// K-loop's __syncthreads drains vmcnt(0) -> prefetch never survives the
// barrier (same defect R16 fixed in flash, +38-73% on GEMM in learn_hip m218).
// Now: triple-buffer sA/sB, one raw s_barrier per K-step, vmcnt(4|3) retires
// exactly tile t's loads (t+1,t+2 in flight, 2-K-step latency cover),
// sched_barrier(0) fence. Biases preloaded + value-pinned BEFORE stage(0) so
// the vmcnt FIFO holds staging loads only. MODE2's trb OVERLAYS smem (post-
// loop use only, __syncthreads-guarded) -> gemm2 keeps 3 blk/CU at 48KB.
// Flash = R18 exactly (control: ~168us, FETCH 28.8MB).
typedef __hip_bfloat16 bf16;
typedef __attribute__((ext_vector_type(8))) short s8v;    // 8 x bf16 (4 VGPRs)
typedef __attribute__((ext_vector_type(4))) float f4v;    // 16x16 accum
typedef __attribute__((ext_vector_type(16))) float f16v;  // 32x32 accum

__device__ __forceinline__ void gld16(const bf16* g, bf16* l) {
  __builtin_amdgcn_global_load_lds(
      (__attribute__((address_space(1))) unsigned int*)g,
      (__attribute__((address_space(3))) unsigned int*)l, 16, 0, 0);
}

__device__ __forceinline__ f4v mfma16(s8v a, s8v b, f4v c) {
  return __builtin_amdgcn_mfma_f32_16x16x32_bf16(a, b, c, 0, 0, 0);
}

__device__ __forceinline__ f16v mfma32(s8v a, s8v b, f16v c) {
  return __builtin_amdgcn_mfma_f32_32x32x16_bf16(a, b, c, 0, 0, 0);
}

__device__ __forceinline__ unsigned short f2bfu(float f) {
  union { bf16 h; unsigned short u; } cv;
  cv.h = __float2bfloat16(f);
  return cv.u;
}

// ---------------- prep: hs fp32->bf16 + 8 weight transposes + bias concat ----------------
__global__ __launch_bounds__(256) void prep(
    const float* __restrict__ hs, bf16* __restrict__ hsb,
    const float* __restrict__ bdkv, const float* __restrict__ bdq,
    const float* __restrict__ bkr, const float* __restrict__ bqr,
    float* __restrict__ bcat,
    const float* __restrict__ wdkv, bf16* __restrict__ tdkv,
    const float* __restrict__ wdq,  bf16* __restrict__ tdq,
    const float* __restrict__ wkr,  bf16* __restrict__ tkr,
    const float* __restrict__ wqr,  bf16* __restrict__ tqr,
    const float* __restrict__ wuk,  bf16* __restrict__ tuk,
    const float* __restrict__ wuv,  bf16* __restrict__ tuv,
    const float* __restrict__ wuq,  bf16* __restrict__ tuq,
    const float* __restrict__ wo,   bf16* __restrict__ to_) {
  int bid = blockIdx.x;
  int tid = threadIdx.x;
  if (bid < 4096) {
    int i = (bid * 256 + tid) * 8;
    union { s8v v; unsigned short u[8]; } pk;
#pragma unroll
    for (int j = 0; j < 8; j++) pk.u[j] = f2bfu(hs[i + j]);
    *(s8v*)(hsb + i) = pk.v;
    return;
  }
  if (bid == 4096) {
#pragma unroll
    for (int p = 0; p < 5; p++) {
      int i = tid + p * 256;
      float v;
      if (i < 512)       v = bdkv[i];
      else if (i < 1024) v = bdq[i - 512];
      else if (i < 1152) v = bkr[i - 1024];
      else               v = bqr[i - 1152];
      bcat[i] = v;
    }
    return;
  }
  bid -= 4097;
  const float* src; bf16* dst; int R, C;
  if      (bid < 1024) { src = wdkv; dst = tdkv; R = 2048; C = 512;  }
  else if (bid < 2048) { src = wdq;  dst = tdq;  R = 2048; C = 512;  bid -= 1024; }
  else if (bid < 2304) { src = wkr;  dst = tkr;  R = 2048; C = 128;  bid -= 2048; }
  else if (bid < 2560) { src = wqr;  dst = tqr;  R = 2048; C = 128;  bid -= 2304; }
  else if (bid < 3584) { src = wuk;  dst = tuk;  R = 512;  C = 2048; bid -= 2560; }
  else if (bid < 4608) { src = wuv;  dst = tuv;  R = 512;  C = 2048; bid -= 3584; }
  else if (bid < 5632) { src = wuq;  dst = tuq;  R = 512;  C = 2048; bid -= 4608; }
  else                 { src = wo;   dst = to_;  R = 2048; C = 2048; bid -= 5632; }
  __shared__ float t[32][33];
  int C32 = C >> 5;
  int bx = bid % C32, by = bid / C32;
  int tx = tid & 31, ty = tid >> 5;
  int c0 = bx * 32, r0 = by * 32;
#pragma unroll
  for (int i = 0; i < 32; i += 8)
    t[ty + i][tx] = src[(size_t)(r0 + ty + i) * C + c0 + tx];
  __syncthreads();
#pragma unroll
  for (int i = 0; i < 32; i += 8)
    dst[(size_t)(c0 + ty + i) * R + r0 + tx] = __float2bfloat16(t[tx][ty + i]);
}

// ---------------- rope (both k and q in one launch) ----------------
__global__ void rope_kernel(const bf16* __restrict__ inK, bf16* __restrict__ outK,
                            const bf16* __restrict__ inQ, bf16* __restrict__ outQ) {
  const bf16* in = (blockIdx.y == 0) ? inK : inQ;
  bf16* out = (blockIdx.y == 0) ? outK : outQ;
  int row = blockIdx.x;       // b*2048 + s
  int d = threadIdx.x;        // 0..63
  int pos = row & 2047;
  float x1 = __bfloat162float(in[(size_t)row * 128 + d]);
  float x2 = __bfloat162float(in[(size_t)row * 128 + 64 + d]);
  float inv = exp2f(-(float)d * (13.287712379549449f / 64.0f));  // 10000^(-d/64)
  float ang = (float)pos * inv;
  float sn = sinf(ang), cs = cosf(ang);
  out[(size_t)row * 128 + d]      = __float2bfloat16(x1 * cs - x2 * sn);
  out[(size_t)row * 128 + 64 + d] = __float2bfloat16(x1 * sn + x2 * cs);
}

// ---------------- GEMM: C(MxN) = A(MxK) @ Bt(NxK)^T + bias ----------------
// 128xNT tile, BK=32, 4 waves (2x2), global_load_lds w=16, TRIPLE-buffered
// sA/sB with counted-vmcnt single-barrier K-loop (R16 scheme). XCD-chunked
// block swizzle (grid %8==0). MODE2 trb overlays smem (post-loop only).
template <int MODE, int NT>
__global__ __launch_bounds__(256) void gemm_bt(
    const bf16* __restrict__ A, const bf16* __restrict__ A2,
    const bf16* __restrict__ Bt,
    const float* __restrict__ b0, const float* __restrict__ b1,
    const float* __restrict__ b2,
    void* __restrict__ C0, void* __restrict__ C1,
    void* __restrict__ C2, void* __restrict__ C3,
    int M, int N, int K) {
  constexpr int WN = NT / 2;        // per-wave n extent
  constexpr int NJ = WN / 16;       // per-wave 16-col tiles
  constexpr int BUFE = 128 * 32 + NT * 32;  // elements per buffer (A+B)
  __shared__ __align__(16) bf16 smem[3 * BUFE];
  const int tid = threadIdx.x, lane = tid & 63, wid = tid >> 6;
  const int l15 = lane & 15, l4 = lane >> 4;
  // XCD-chunked swizzle (bijective when nwg%8==0)
  const int nwg = gridDim.x * gridDim.y;
  int bid = blockIdx.x + gridDim.x * blockIdx.y;
  bid = (bid & 7) * (nwg >> 3) + (bid >> 3);
  const int m0 = (bid / gridDim.x) * 128, n0 = (bid % gridDim.x) * NT;
  const int wm = (wid >> 1) * 64, wn = (wid & 1) * WN;
  f4v acc[4][NJ] = {};
  const bf16* Ause = (MODE == 2 && n0 >= 4096) ? A2 : A;
  const bf16* gA = Ause + (size_t)m0 * K;
  const bf16* gB = Bt + (size_t)n0 * K;

  // --- bias preload (before the pipeline; value-pinned so these loads retire
  // here and never sit in the vmcnt FIFO during the loop) ---
  float bv[NJ];
#pragma unroll
  for (int j = 0; j < NJ; j++) {
    const int nb = n0 + wn + j * 16;
    const int n = nb + l15;
    if (MODE == 2)
      bv[j] = (nb < 2048) ? b0[n] : ((nb < 4096) ? b1[n - 2048] : b2[n - 4096]);
    else
      bv[j] = b0[n];   // MODE1: bcat concat; MODE3: b_O
  }
#pragma unroll
  for (int j = 0; j < NJ; j++) asm volatile("" : "+v"(bv[j]));
  __builtin_amdgcn_sched_barrier(0);

  const int row = tid >> 2, col = (tid & 3) * 8;
  auto stageg = [&](int buf, int k0) {
    bf16* bA = smem + buf * BUFE;
    bf16* bB = bA + 128 * 32;
    gld16(gA + (size_t)row * K + k0 + col,        bA + tid * 8);
    gld16(gA + (size_t)(row + 64) * K + k0 + col, bA + (tid + 256) * 8);
    gld16(gB + (size_t)row * K + k0 + col,        bB + tid * 8);
    if (NT == 128)
      gld16(gB + (size_t)(row + 64) * K + k0 + col, bB + (tid + 256) * 8);
  };

  const int NK = K >> 5;
  stageg(0, 0);
  stageg(1, 32);
  for (int it = 0; it < NK; ++it) {
    // retire exactly tile it's loads (t+1[,t+2] stay in flight); last iter
    // drains fully (reorder-proof).
    if (it < NK - 1) {
      if constexpr (NT == 128) asm volatile("s_waitcnt vmcnt(4)" ::: "memory");
      else                     asm volatile("s_waitcnt vmcnt(3)" ::: "memory");
    } else {
      asm volatile("s_waitcnt vmcnt(0)" ::: "memory");
    }
    __builtin_amdgcn_s_barrier();
    __builtin_amdgcn_sched_barrier(0);   // no ds_read hoisted above the sync
    if (it + 2 < NK) stageg((it + 2) % 3, (it + 2) * 32);
    const bf16* cA = smem + (it % 3) * BUFE;
    const bf16* cB = cA + 128 * 32;
    s8v a[4], b[NJ];
#pragma unroll
    for (int i = 0; i < 4; i++) a[i] = *(const s8v*)(cA + (wm + i * 16 + l15) * 32 + l4 * 8);
#pragma unroll
    for (int j = 0; j < NJ; j++) b[j] = *(const s8v*)(cB + (wn + j * 16 + l15) * 32 + l4 * 8);
#pragma unroll
    for (int i = 0; i < 4; i++)
#pragma unroll
      for (int j = 0; j < NJ; j++) acc[i][j] = mfma16(a[i], b[j], acc[i][j]);
    // no trailing barrier: buf (it+2)%3 overwrite is fenced by the top barrier
  }

  // ---- MODE 2 vT region: per-wave LDS transpose (overlays smem), coalesced stores ----
  if (MODE == 2 && n0 >= 2048 && n0 < 4096) {
    __syncthreads();                       // all waves done reading smem K-bufs
    bf16* tb = smem + wid * (64 * 72);     // 4 waves x 64x72 = 36KB < 48KB
    const int nn0 = n0 - 2048;             // multiple of 128
    const int hh = nn0 >> 7;               // head within vT
    const int bb = m0 >> 11;
    const int ss0 = (m0 & 2047) + wm;      // s base of this wave's quadrant
    // write acc -> tb[d_rel][s_rel] (d_rel = j*16+l15, s_rel = i*16+l4*4+g)
#pragma unroll
    for (int j = 0; j < NJ; j++) {
#pragma unroll
      for (int i = 0; i < 4; i++) {
        uint2 w;
        w.x = (unsigned int)f2bfu(acc[i][j][0] + bv[j]) | ((unsigned int)f2bfu(acc[i][j][1] + bv[j]) << 16);
        w.y = (unsigned int)f2bfu(acc[i][j][2] + bv[j]) | ((unsigned int)f2bfu(acc[i][j][3] + bv[j]) << 16);
        *(uint2*)(tb + (j * 16 + l15) * 72 + i * 16 + l4 * 4) = w;
      }
    }
    asm volatile("s_waitcnt lgkmcnt(0)" ::: "memory");
    __builtin_amdgcn_sched_barrier(0);
    // read straight rows (b128) + store: 8 lanes x 16B = 128B contiguous per d-row
    const int dl = lane >> 3, sl = (lane & 7) * 8;
    bf16* dstbase = (bf16*)C1 +
        ((size_t)(bb * 16 + hh) * 128 + wn) * 2048 + ss0;
#pragma unroll
    for (int r = 0; r < 8; r++) {
      int d_rel = r * 8 + dl;
      s8v v = *(const s8v*)(tb + d_rel * 72 + sl);
      *(s8v*)(dstbase + (size_t)d_rel * 2048 + sl) = v;
    }
    return;
  }
  // epilogue. C/D layout: row = l4*4+g, col = l15 (within 16x16 tile)
#pragma unroll
  for (int j = 0; j < NJ; j++) {
    const int nb = n0 + wn + j * 16;      // 16-col tile base (uniform per j)
    const int n = nb + l15;
    if (MODE == 3) {
#pragma unroll
      for (int i = 0; i < 4; i++) {
        size_t mb = m0 + wm + i * 16 + l4 * 4;
#pragma unroll
        for (int g = 0; g < 4; g++)
          ((float*)C0)[(mb + g) * (size_t)N + n] = acc[i][j][g] + bv[j];
      }
    } else if (MODE == 1) {
      bf16* dst; int stride, nc;
      if (nb < 512)       { dst = (bf16*)C0; stride = 512; nc = n; }
      else if (nb < 1024) { dst = (bf16*)C1; stride = 512; nc = n - 512; }
      else if (nb < 1152) { dst = (bf16*)C2; stride = 128; nc = n - 1024; }
      else                { dst = (bf16*)C3; stride = 128; nc = n - 1152; }
#pragma unroll
      for (int i = 0; i < 4; i++) {
        size_t mb = m0 + wm + i * 16 + l4 * 4;
#pragma unroll
        for (int g = 0; g < 4; g++)
          dst[(mb + g) * (size_t)stride + nc] = __float2bfloat16(acc[i][j][g] + bv[j]);
      }
    } else {  // MODE 2: UK (k_c, nb<2048) | UQ (q_c, nb>=4096); vT handled above
      if (nb < 2048) {
        bf16* dst = (bf16*)C0;
#pragma unroll
        for (int i = 0; i < 4; i++) {
          size_t mb = m0 + wm + i * 16 + l4 * 4;
#pragma unroll
          for (int g = 0; g < 4; g++)
            dst[(mb + g) * (size_t)2048 + n] = __float2bfloat16(acc[i][j][g] + bv[j]);
        }
      } else {
        bf16* dst = (bf16*)C2;
        int nn = n - 4096;
#pragma unroll
        for (int i = 0; i < 4; i++) {
          size_t mb = m0 + wm + i * 16 + l4 * 4;
#pragma unroll
          for (int g = 0; g < 4; g++)
            dst[(mb + g) * (size_t)2048 + nn] = __float2bfloat16(acc[i][j][g] + bv[j]);
        }
      }
    }
  }
}

// ---------------- flash attention (32x32 MFMA, counted-vmcnt pipeline, XCD swizzle) ----------------
// grid (S/128, B*NH), 256 thr (4 waves; wave owns 32 q-rows). BN=32 keys/iter.
// LDS: TRIPLE-buffered sK/sKr/sVT (8KB each) -> 72KB, 2 blocks/CU. Sync per
// iter: s_waitcnt vmcnt(10) -> raw s_barrier -> sched_barrier(0); stage(t+2)
// + mask(t+1) after -> ~2 compute phases of latency cover (R16-proven).
// XCD swizzle: chunked remap gives each XCD 4 whole heads (R17: FETCH 5x cut).
__global__ __launch_bounds__(256, 2) void flash_attn(
    const bf16* __restrict__ Qc, const bf16* __restrict__ Kc,
    const bf16* __restrict__ Qr, const bf16* __restrict__ Kr,
    const bf16* __restrict__ VT, const int* __restrict__ amask,
    bf16* __restrict__ ctx) {
  const int S = 2048, H = 2048, D = 128;
  __shared__ bf16 sK[3][16 * 32 * 8];
  __shared__ bf16 sKr[3][16 * 32 * 8];
  __shared__ bf16 sVT[3][4 * 128 * 8];

  const int tid = threadIdx.x, lane = tid & 63, wid = tid >> 6;
  const int l31 = lane & 31, hi = lane >> 5;
  // XCD-chunked remap (bijective on 512 = 8*64): XCD c gets heads 4c..4c+3
  const int phys = blockIdx.x + 16 * blockIdx.y;
  const int lid  = (phys & 7) * 64 + (phys >> 3);
  const int qt = lid & 15, bh = lid >> 4;
  const int b = bh >> 4, h = bh & 15;
  const size_t bS = (size_t)b * S;
  const int q0 = qt * 128 + wid * 32;

  // Q fragments (B-operand of swapped QK): q = q0+l31, k(d) = t*16 + hi*8 + j
  s8v qcf[8], qrf[8];
  {
    const bf16* pc = Qc + (bS + q0 + l31) * H + h * D + hi * 8;
    const bf16* pr = Qr + (bS + q0 + l31) * D + hi * 8;
#pragma unroll
    for (int t = 0; t < 8; t++) {
      qcf[t] = *(const s8v*)(pc + t * 16);
      qrf[t] = *(const s8v*)(pr + t * 16);
    }
  }

  f16v oacc[4] = {};   // [dblk]: col=l31 -> d=dblk*32+l31; row(reg)=q pattern
  float lsum = 0.f;
  const float scl = 0.08838834764831845f;  // 1/sqrt(128)

  auto stage = [&](int buf, int kv) {
#pragma unroll
    for (int p = 0; p < 2; p++) {
      int idx = tid + p * 256;
      int key = (idx & 31), dch = (idx >> 5);
      gld16(Kc + (bS + kv + key) * H + h * D + dch * 8, sK[buf] + idx * 8);
      gld16(Kr + (bS + kv + key) * D + dch * 8, sKr[buf] + idx * 8);
      int d = (idx & 127), kch = (idx >> 7);
      gld16(VT + ((size_t)bh * D + d) * S + kv + kch * 8, sVT[buf] + idx * 8);
    }
  };

  const int xaddr = (lane ^ 32) * 4;   // bpermute: partner lane (hi flip)

  // prologue: stage tiles 0,1 + masks for tile 0 (queue: st0[6] mv0[4] st1[6])
  int4 mvC[4], mvN[4];
  stage(0, 0);
#pragma unroll
  for (int g2 = 0; g2 < 4; g2++)
    mvC[g2] = *(const int4*)(amask + bS + 8 * g2 + 4 * hi);
  stage(1, 32);

  for (int it = 0; it < 64; ++it) {
    const int cur = it % 3;
    const int kv0 = it * 32;
    // wait for tile `it` only: outstanding <= st(it)[6]+mv(it)[4]+st(it+1)[6];
    // vmcnt(10) retires the oldest 6 = st(it). Last iter: full drain.
    if (it < 63) asm volatile("s_waitcnt vmcnt(10)" ::: "memory");
    else         asm volatile("s_waitcnt vmcnt(0)" ::: "memory");
    __builtin_amdgcn_s_barrier();
    __builtin_amdgcn_sched_barrier(0);   // no ds_read hoisted above the sync

    // prefetch mask(t+1) then stage(t+2) (order keeps st(t+1) older than both)
    if (it + 1 < 64) {
#pragma unroll
      for (int g2 = 0; g2 < 4; g2++)
        mvN[g2] = *(const int4*)(amask + bS + kv0 + 32 + 8 * g2 + 4 * hi);
    } else {
#pragma unroll
      for (int g2 = 0; g2 < 4; g2++) mvN[g2] = mvC[g2];
    }
    if (it + 2 < 64) stage((it + 2) % 3, kv0 + 64);

    // S^T = Kc.Qc^T + Kr.Qr^T (swapped, 32x32x16): A row=key=l31, k=hi*8+j ->
    // d = t*16+hi*8+j -> sK[dch=2t+hi][key=l31]. Two accs = 2 indep chains.
    f16v scc = {}, scr = {};
    __builtin_amdgcn_s_setprio(1);
#pragma unroll
    for (int t = 0; t < 8; t++) {
      s8v kf = *(const s8v*)(sK[cur] + ((2 * t + hi) * 32 + l31) * 8);
      scc = mfma32(kf, qcf[t], scc);
      s8v rf = *(const s8v*)(sKr[cur] + ((2 * t + hi) * 32 + l31) * 8);
      scr = mfma32(rf, qrf[t], scr);
    }
    __builtin_amdgcn_s_setprio(0);

    // no-max softmax over lane's 16 keys: reg r -> key (r&3)+8*(r>>2)+4*hi.
    // pk2[g2][w] packs keys 8*g2+4*hi+{2w,2w+1} (consecutive).
    unsigned int pk2[4][2];
#pragma unroll
    for (int g2 = 0; g2 < 4; g2++) {
      const int* mm = (const int*)&mvC[g2];
#pragma unroll
      for (int w = 0; w < 2; w++) {
        int r = 4 * g2 + 2 * w;
        float pa = mm[2 * w]     ? __expf((scc[r] + scr[r]) * scl) : 0.f;
        float pb = mm[2 * w + 1] ? __expf((scc[r + 1] + scr[r + 1]) * scl) : 0.f;
        lsum += pa + pb;
        pk2[g2][w] = (unsigned int)f2bfu(pa) | ((unsigned int)f2bfu(pb) << 16);
      }
    }

    // PV A-frag (q=l31, k=16*ks+8*hi+j): own run g2=2ks+hi + partner's same-g2
    // half. Lane passes its g2=2ks+(hi^1) packs; receives partner's g2=2ks+hi.
    s8v pf[2];
#pragma unroll
    for (int ks = 0; ks < 2; ks++) {
      int passA = hi ? (int)pk2[2 * ks][0] : (int)pk2[2 * ks + 1][0];
      int passB = hi ? (int)pk2[2 * ks][1] : (int)pk2[2 * ks + 1][1];
      int recvA = __builtin_amdgcn_ds_bpermute(xaddr, passA);
      int recvB = __builtin_amdgcn_ds_bpermute(xaddr, passB);
      union { int w[4]; s8v v; } u;
      u.w[0] = hi ? recvA : (int)pk2[2 * ks][0];
      u.w[1] = hi ? recvB : (int)pk2[2 * ks][1];
      u.w[2] = hi ? (int)pk2[2 * ks + 1][0] : recvA;
      u.w[3] = hi ? (int)pk2[2 * ks + 1][1] : recvB;
      pf[ks] = u.v;
    }

    // O += P @ V (32x32x16): B col=l31=d, k=hi*8+j -> key=16ks+8hi+j ->
    // sVT[kch=2ks+hi][d]. 4 indep acc chains (dblk), depth 2.
    __builtin_amdgcn_s_setprio(1);
#pragma unroll
    for (int dblk = 0; dblk < 4; dblk++) {
      s8v vf0 = *(const s8v*)(sVT[cur] + ((0 + hi) * 128 + dblk * 32 + l31) * 8);
      oacc[dblk] = mfma32(pf[0], vf0, oacc[dblk]);
      s8v vf1 = *(const s8v*)(sVT[cur] + ((2 + hi) * 128 + dblk * 32 + l31) * 8);
      oacc[dblk] = mfma32(pf[1], vf1, oacc[dblk]);
    }
    __builtin_amdgcn_s_setprio(0);

#pragma unroll
    for (int g2 = 0; g2 < 4; g2++) mvC[g2] = mvN[g2];
  }

  // row sums: lane's lsum covers 16 of 32 keys/iter for q=l31; partner (^32)
  // has the rest -> one xor reduce gives the full sum per q=l31.
  float s = lsum;
  s += __shfl_xor(s, 32, 64);
  float inv[16];
#pragma unroll
  for (int g = 0; g < 16; g++) {
    int ql = (g & 3) + 8 * (g >> 2) + 4 * hi;   // oacc reg g's q (0..31)
    inv[g] = 1.0f / __shfl(s, ql, 64);
  }

  // normalize + store ctx (B,S,H): oacc[dblk][g] -> q=pattern, d=dblk*32+l31
#pragma unroll
  for (int dblk = 0; dblk < 4; dblk++)
#pragma unroll
    for (int g = 0; g < 16; g++) {
      int qrow = q0 + (g & 3) + 8 * (g >> 2) + 4 * hi;
      ctx[(bS + qrow) * H + h * D + dblk * 32 + l31] =
          __float2bfloat16(oacc[dblk][g] * inv[g]);
    }
}

// ---------------- launch ----------------
extern "C" void kernel_launch(void* const* d_in, const int* in_sizes, int n_in,
                              void* d_out, int out_size, void* d_ws, size_t ws_size,
                              hipStream_t stream) {
  const float* hs    = (const float*)d_in[0];
  const int*   amask = (const int*)d_in[1];
  const float* W_DKV = (const float*)d_in[2];  const float* b_DKV = (const float*)d_in[3];
  const float* W_DQ  = (const float*)d_in[4];  const float* b_DQ  = (const float*)d_in[5];
  const float* W_UK  = (const float*)d_in[6];  const float* b_UK  = (const float*)d_in[7];
  const float* W_UV  = (const float*)d_in[8];  const float* b_UV  = (const float*)d_in[9];
  const float* W_UQ  = (const float*)d_in[10]; const float* b_UQ  = (const float*)d_in[11];
  const float* W_KR  = (const float*)d_in[12]; const float* b_KR  = (const float*)d_in[13];
  const float* W_QR  = (const float*)d_in[14]; const float* b_QR  = (const float*)d_in[15];
  const float* W_O   = (const float*)d_in[16]; const float* b_O   = (const float*)d_in[17];

  char* wsb = (char*)d_ws;
  size_t off = 0;
  auto allocB = [&](size_t bytes) {
    void* p = wsb + off; off = (off + bytes + 255) & ~(size_t)255; return p;
  };
  float* bcat  = (float*)allocB(1280 * 4);
  bf16* hsb    = (bf16*)allocB((size_t)4096 * 2048 * 2);
  bf16* wt_dkv = (bf16*)allocB((size_t)512 * 2048 * 2);
  bf16* wt_dq  = (bf16*)allocB((size_t)512 * 2048 * 2);
  bf16* wt_kr  = (bf16*)allocB((size_t)128 * 2048 * 2);
  bf16* wt_qr  = (bf16*)allocB((size_t)128 * 2048 * 2);
  // wt_uk|wt_uv|wt_uq MUST stay contiguous (single Bt for the merged GEMM):
  bf16* wt_uk  = (bf16*)allocB((size_t)2048 * 512 * 2);
  bf16* wt_uv  = (bf16*)allocB((size_t)2048 * 512 * 2);
  bf16* wt_uq  = (bf16*)allocB((size_t)2048 * 512 * 2);
  bf16* wt_o   = (bf16*)allocB((size_t)2048 * 2048 * 2);
  bf16* c_kv   = (bf16*)allocB((size_t)4096 * 512 * 2);
  bf16* c_q    = (bf16*)allocB((size_t)4096 * 512 * 2);
  bf16* krl    = (bf16*)allocB((size_t)4096 * 128 * 2);
  bf16* qrl    = (bf16*)allocB((size_t)4096 * 128 * 2);
  bf16* k_r    = (bf16*)allocB((size_t)4096 * 128 * 2);
  bf16* q_r    = (bf16*)allocB((size_t)4096 * 128 * 2);
  bf16* k_c    = (bf16*)allocB((size_t)4096 * 2048 * 2);
  bf16* q_c    = (bf16*)allocB((size_t)4096 * 2048 * 2);
  bf16* vT     = (bf16*)allocB((size_t)4096 * 2048 * 2);
  bf16* ctx    = (bf16*)allocB((size_t)4096 * 2048 * 2);
  (void)wt_uv; (void)wt_uq;

  // one-shot ingest: 4096 hs-convert + 1 bias-concat + 9728 transpose tiles
  prep<<<13825, 256, 0, stream>>>(hs, hsb,
      b_DKV, b_DQ, b_KR, b_QR, bcat,
      W_DKV, wt_dkv, W_DQ, wt_dq, W_KR, wt_kr, W_QR, wt_qr,
      W_UK, wt_uk, W_UV, wt_uv, W_UQ, wt_uq, W_O, wt_o);

  // fused projections: N = 512|512|128|128 = 1280, K = 2048.
  // NT=64 tile -> 640 blocks (2.5/CU)
  gemm_bt<1, 64><<<dim3(20, 32), 256, 0, stream>>>(
      hsb, nullptr, wt_dkv, bcat, nullptr, nullptr,
      c_kv, c_q, krl, qrl, 4096, 1280, 2048);
  rope_kernel<<<dim3(4096, 2), 64, 0, stream>>>(krl, k_r, qrl, q_r);

  // merged UK|UV|UQ: N = 2048*3 = 6144, K = 512 (A = c_kv for n<4096, c_q above)
  gemm_bt<2, 128><<<dim3(48, 32), 256, 0, stream>>>(
      c_kv, c_q, wt_uk, b_UK, b_UV, b_UQ,
      k_c, vT, q_c, nullptr, 4096, 6144, 512);

  // attention: grid (2048/128, 32) = 512 blocks, 2 blocks/CU (72KB LDS)
  flash_attn<<<dim3(16, 32), 256, 0, stream>>>(q_c, k_c, q_r, k_r, vT, amask, ctx);

  // output projection (fp32 out)
  gemm_bt<3, 128><<<dim3(16, 32), 256, 0, stream>>>(
      ctx, nullptr, wt_o, b_O, nullptr, nullptr,
      d_out, nullptr, nullptr, nullptr, 4096, 2048, 2048);
}